// Round 6
// baseline (912.217 us; speedup 1.0000x reference)
//
#include <hip/hip_runtime.h>
#include <math.h>

#define Bn 128
#define Nn 512
#define Cc 7
#define Hh 64
#define Kk 16
#define Rr 2
#define EPSf 1e-5f

typedef __attribute__((ext_vector_type(8))) short bf16x8;
typedef __attribute__((ext_vector_type(4))) float f32x4;

#define PLN ((size_t)4194304)   // elements per h-split plane (B*N*H)

// exact truncation split: a = hi + mid + lo + r, |r| <= 2^-24 |a|
__device__ __forceinline__ void split3(float a, short &hs, short &ms, short &ls) {
    unsigned u  = __float_as_uint(a);
    unsigned hu = u & 0xFFFF0000u;
    float r1 = a - __uint_as_float(hu);
    unsigned mu = __float_as_uint(r1) & 0xFFFF0000u;
    float r2 = r1 - __uint_as_float(mu);
    unsigned lu = __float_as_uint(r2) & 0xFFFF0000u;
    hs = (short)(hu >> 16); ms = (short)(mu >> 16); ls = (short)(lu >> 16);
}

#define MFMA6(acc, AH, AM, AL, BH, BM, BL) \
    acc = __builtin_amdgcn_mfma_f32_16x16x32_bf16(AL, BH, acc, 0, 0, 0); \
    acc = __builtin_amdgcn_mfma_f32_16x16x32_bf16(AM, BM, acc, 0, 0, 0); \
    acc = __builtin_amdgcn_mfma_f32_16x16x32_bf16(AH, BL, acc, 0, 0, 0); \
    acc = __builtin_amdgcn_mfma_f32_16x16x32_bf16(AM, BH, acc, 0, 0, 0); \
    acc = __builtin_amdgcn_mfma_f32_16x16x32_bf16(AH, BM, acc, 0, 0, 0); \
    acc = __builtin_amdgcn_mfma_f32_16x16x32_bf16(AH, BH, acc, 0, 0, 0);

// ---------------------------------------------------------------------------
// prep: split W per round into Wd (bf16x3) and Wc-Wd (bf16x3) planes.
// ---------------------------------------------------------------------------
__global__ void k_prep(const float* __restrict__ w_nb, short* __restrict__ wS)
{
    int i = blockIdx.x * 256 + threadIdx.x;     // 0 .. 2*64*64-1
    int r = i >> 12, oc = i & 4095;
    int o = oc >> 6, c = oc & 63;
    const float* wr = w_nb + (size_t)r * Hh * 2 * Hh + (size_t)o * 2 * Hh;
    float wc = wr[c], wd = wr[Hh + c];
    short* base = wS + (size_t)r * 6 * 4096;
    short h_, m_, l_;
    split3(wd, h_, m_, l_);
    base[0 * 4096 + oc] = h_; base[1 * 4096 + oc] = m_; base[2 * 4096 + oc] = l_;
    split3(wc - wd, h_, m_, l_);
    base[3 * 4096 + oc] = h_; base[4 * 4096 + oc] = m_; base[5 * 4096 + oc] = l_;
}

// ---------------------------------------------------------------------------
// t1 + t2 fused (h values bit-identical to prior rounds) + split-plane output
// ---------------------------------------------------------------------------
__global__ __launch_bounds__(256) void k_t12(
    const float* __restrict__ x,
    const float* __restrict__ w1, const float* __restrict__ g1, const float* __restrict__ b1,
    const float* __restrict__ w2, const float* __restrict__ g2, const float* __restrict__ b2,
    float* __restrict__ h, short* __restrict__ hS, float* __restrict__ sq)
{
    int t = threadIdx.x;
    int grp = t >> 6, o = t & 63;
    int p = blockIdx.x * 4 + grp;
    int b = p >> 9, n = p & 511;

    __shared__ float h1s[4][64];
    const float inv = rsqrtf(1.0f + EPSf);

    float acc = 0.0f;
#pragma unroll
    for (int c = 0; c < Cc; ++c)
        acc = fmaf(w1[o * Cc + c], x[(b * Cc + c) * Nn + n], acc);
    acc = fmaf(acc, g1[o] * inv, b1[o]);
    acc = fmaxf(acc, 0.0f);
    h1s[grp][o] = acc;
    __syncthreads();

    float a2 = 0.0f;
#pragma unroll 8
    for (int c = 0; c < Hh; ++c)
        a2 = fmaf(w2[o * Hh + c], h1s[grp][c], a2);
    a2 = fmaf(a2, g2[o] * inv, b2[o]);
    a2 = fmaxf(a2, 0.0f);
    h[(size_t)p * Hh + o] = a2;
    short hs_, ms_, ls_;
    split3(a2, hs_, ms_, ls_);
    hS[0 * PLN + (size_t)p * Hh + o] = hs_;
    hS[1 * PLN + (size_t)p * Hh + o] = ms_;
    hS[2 * PLN + (size_t)p * Hh + o] = ls_;

    float s = a2 * a2;
#pragma unroll
    for (int off = 32; off > 0; off >>= 1) s += __shfl_down(s, off, 64);
    if (o == 0) sq[p] = s;
}

// ---------------------------------------------------------------------------
// kNN: 256 threads, 16 centers/block. Distance: 2 m-rows x 16 ctr per thread
// (128 FMA per 16 broadcast LDS reads). Selection: 4 waves x 4 concurrent
// points (4 interleaved butterfly chains). Distance expression textually
// identical to rounds 2-5 -> bit-identical keys -> identical indices.
// ---------------------------------------------------------------------------
__global__ __launch_bounds__(256) void k_knn(
    const float* __restrict__ h, const float* __restrict__ sq, int* __restrict__ idxout)
{
    int bidx = blockIdx.x;
    int b  = bidx >> 5;                    // 32 tiles per batch
    int n0 = (bidx & 31) << 4;             // 16 centers
    int t  = threadIdx.x;

    __shared__ float4 ctr4[16 * 16];       // 16 centers x 64 ch
    __shared__ unsigned int keysLDS[16 * 512];
    __shared__ float sqc[16];

    const float* hb = h + (size_t)b * Nn * Hh;
    // stage 16 centers: 256 float4, one per thread
    {
        ctr4[t] = ((const float4*)(hb + (size_t)n0 * Hh))[t];
        if (t < 16) sqc[t] = sq[b * Nn + n0 + t];
    }
    __syncthreads();

    {
        int m  = t;
        int m2 = t + 256;
        const float4* hv  = (const float4*)(hb + (size_t)m  * Hh);
        const float4* hv2 = (const float4*)(hb + (size_t)m2 * Hh);
        float dj[16], ej[16];
#pragma unroll
        for (int j = 0; j < 16; ++j) { dj[j] = 0.0f; ej[j] = 0.0f; }
#pragma unroll
        for (int c4 = 0; c4 < 16; ++c4) {
            float4 v  = hv[c4];
            float4 v2 = hv2[c4];
#pragma unroll
            for (int j = 0; j < 16; ++j) {
                float4 cv = ctr4[j * 16 + c4];
                dj[j] += v.x  * cv.x + v.y  * cv.y + v.z  * cv.z + v.w  * cv.w;
                ej[j] += v2.x * cv.x + v2.y * cv.y + v2.z * cv.z + v2.w * cv.w;
            }
        }
        float sm  = sq[b * Nn + m];
        float sm2 = sq[b * Nn + m2];
#pragma unroll
        for (int j = 0; j < 16; ++j) {
            float d = sqc[j] + sm - 2.0f * dj[j];
            unsigned int u = __float_as_uint(d);
            u = ((int)u < 0) ? ~u : (u | 0x80000000u);
            keysLDS[j * 512 + m] = u;

            float d2 = sqc[j] + sm2 - 2.0f * ej[j];
            unsigned int u2 = __float_as_uint(d2);
            u2 = ((int)u2 < 0) ? ~u2 : (u2 | 0x80000000u);
            keysLDS[j * 512 + m2] = u2;
        }
    }
    __syncthreads();

    // selection: wave wvid handles points jj = wvid*4 .. wvid*4+3 concurrently
    int wvid = t >> 6, lane = t & 63;

    unsigned int kk[4][8];
    int rr[4][8];
#pragma unroll
    for (int s = 0; s < 4; ++s) {
        int jj = wvid * 4 + s;
        const uint4* kp = (const uint4*)&keysLDS[jj * 512 + (lane << 3)];
        uint4 A = kp[0], Bq = kp[1];
        kk[s][0] = A.x;  kk[s][1] = A.y;  kk[s][2] = A.z;  kk[s][3] = A.w;
        kk[s][4] = Bq.x; kk[s][5] = Bq.y; kk[s][6] = Bq.z; kk[s][7] = Bq.w;
#pragma unroll
        for (int q = 0; q < 8; ++q) rr[s][q] = q;
    }

#define CE(s, i, j_) { \
    bool sw = (kk[s][i] > kk[s][j_]) || (kk[s][i] == kk[s][j_] && rr[s][i] > rr[s][j_]); \
    unsigned int tk = sw ? kk[s][i] : kk[s][j_]; kk[s][i] = sw ? kk[s][j_] : kk[s][i]; kk[s][j_] = tk; \
    int tr = sw ? rr[s][i] : rr[s][j_]; rr[s][i] = sw ? rr[s][j_] : rr[s][i]; rr[s][j_] = tr; }
#pragma unroll
    for (int s = 0; s < 4; ++s) {
        CE(s,0,1) CE(s,2,3) CE(s,4,5) CE(s,6,7)
        CE(s,0,2) CE(s,1,3) CE(s,4,6) CE(s,5,7)
        CE(s,1,2) CE(s,5,6)
        CE(s,0,4) CE(s,1,5) CE(s,2,6) CE(s,3,7)
        CE(s,2,4) CE(s,3,5)
        CE(s,1,2) CE(s,3,4) CE(s,5,6)
    }
#undef CE

    int outbase[4];
#pragma unroll
    for (int s = 0; s < 4; ++s) outbase[s] = (b * Nn + n0 + wvid * 4 + s) * Kk;

    for (int iter = 0; iter < Kk; ++iter) {
        unsigned int mv[4];
#pragma unroll
        for (int s = 0; s < 4; ++s) mv[s] = kk[s][0];
#pragma unroll
        for (int sh = 1; sh < 64; sh <<= 1) {
#pragma unroll
            for (int s = 0; s < 4; ++s) {
                unsigned int ov = __shfl_xor(mv[s], sh, 64);
                mv[s] = (ov < mv[s]) ? ov : mv[s];
            }
        }
#pragma unroll
        for (int s = 0; s < 4; ++s) {
            unsigned long long bal = __ballot(kk[s][0] == mv[s]);
            int wn = __ffsll(bal) - 1;
            if (lane == wn) {
                idxout[outbase[s] + iter] = (lane << 3) + rr[s][0];
#pragma unroll
                for (int q = 0; q < 7; ++q) { kk[s][q] = kk[s][q + 1]; rr[s][q] = rr[s][q + 1]; }
                kk[s][7] = 0xFFFFFFFFu;
            }
        }
    }
}

// ---------------------------------------------------------------------------
// EdgeConv via MFMA, base/delta decomposition (unchanged from round 5)
// ---------------------------------------------------------------------------
__global__ __launch_bounds__(256) void k_edge(
    const float* __restrict__ h, const short* __restrict__ hS,
    const int* __restrict__ idx,
    const short* __restrict__ wS,
    const float* __restrict__ g, const float* __restrict__ bb_,
    float* __restrict__ hout, short* __restrict__ hSout, float* __restrict__ sqout)
{
    __shared__ short wdS[3][64 * 72];
    __shared__ short wcdS[3][64 * 72];
    __shared__ float baseS[16 * 68];
    __shared__ int   idxS[256];

    int t  = threadIdx.x;
    int p0 = blockIdx.x * 16;
    int b  = p0 >> 9;

    idxS[t] = idx[p0 * Kk + t];
#pragma unroll
    for (int it = 0; it < 12; ++it) {
        int f = it * 256 + t;              // uint4 index 0..3071
        int plane = f >> 9;                // 0..5
        int i8 = f & 511;
        int o = i8 >> 3, c8 = i8 & 7;
        uint4 v = ((const uint4*)(wS + (size_t)plane * 4096))[i8];
        short* dst = (plane < 3) ? &wdS[plane][0] : &wcdS[plane - 3][0];
        *(uint4*)&dst[o * 72 + c8 * 8] = v;
    }
    __syncthreads();

    int wv = t >> 6, lane = t & 63, col = lane & 15, quad = lane >> 4;

    // ---- base phase: wave wv computes nt=wv tile of base[16 pts][16 o] ----
    {
        f32x4 bacc = (f32x4){0.f, 0.f, 0.f, 0.f};
        const short* hrow = hS + (size_t)(p0 + col) * Hh;
#pragma unroll
        for (int ks = 0; ks < 2; ++ks) {
            int aoff = ks * 32 + quad * 8;
            bf16x8 AH = *(const bf16x8*)(hrow + 0 * PLN + aoff);
            bf16x8 AM = *(const bf16x8*)(hrow + 1 * PLN + aoff);
            bf16x8 AL = *(const bf16x8*)(hrow + 2 * PLN + aoff);
            int boff = (wv * 16 + col) * 72 + aoff;
            bf16x8 BH = *(bf16x8*)&wcdS[0][boff];
            bf16x8 BM = *(bf16x8*)&wcdS[1][boff];
            bf16x8 BL = *(bf16x8*)&wcdS[2][boff];
            MFMA6(bacc, AH, AM, AL, BH, BM, BL)
        }
#pragma unroll
        for (int r_ = 0; r_ < 4; ++r_)
            baseS[(quad * 4 + r_) * 68 + wv * 16 + col] = bacc[r_];
    }
    __syncthreads();

    const float inv = rsqrtf(1.0f + EPSf);
    float scv[4], bov[4];
#pragma unroll
    for (int nt = 0; nt < 4; ++nt) {
        scv[nt] = g[nt * 16 + col] * inv;
        bov[nt] = bb_[nt * 16 + col];
    }

    for (int pr = 0; pr < 2; ++pr) {
        bf16x8 A[2][2][3];
#pragma unroll
        for (int pt2 = 0; pt2 < 2; ++pt2) {
            int pl = wv * 4 + pr * 2 + pt2;
            int j = idxS[pl * 16 + col];
            const short* nrow = hS + ((size_t)(b * Nn) + j) * Hh;
#pragma unroll
            for (int ks = 0; ks < 2; ++ks) {
                int aoff = ks * 32 + quad * 8;
                A[pt2][ks][0] = *(const bf16x8*)(nrow + 0 * PLN + aoff);
                A[pt2][ks][1] = *(const bf16x8*)(nrow + 1 * PLN + aoff);
                A[pt2][ks][2] = *(const bf16x8*)(nrow + 2 * PLN + aoff);
            }
        }

        f32x4 acc[2][4];
#pragma unroll
        for (int pt2 = 0; pt2 < 2; ++pt2)
#pragma unroll
            for (int nt = 0; nt < 4; ++nt)
                acc[pt2][nt] = (f32x4){0.f, 0.f, 0.f, 0.f};

#pragma unroll
        for (int ks = 0; ks < 2; ++ks)
#pragma unroll
            for (int nt = 0; nt < 4; ++nt) {
                int boff = (nt * 16 + col) * 72 + ks * 32 + quad * 8;
                bf16x8 BH = *(bf16x8*)&wdS[0][boff];
                bf16x8 BM = *(bf16x8*)&wdS[1][boff];
                bf16x8 BL = *(bf16x8*)&wdS[2][boff];
#pragma unroll
                for (int pt2 = 0; pt2 < 2; ++pt2) {
                    f32x4 a = acc[pt2][nt];
                    MFMA6(a, A[pt2][ks][0], A[pt2][ks][1], A[pt2][ks][2], BH, BM, BL)
                    acc[pt2][nt] = a;
                }
            }

        // epilogue: m = base + delta; bn per-k; max over k; relu
#pragma unroll
        for (int pt2 = 0; pt2 < 2; ++pt2) {
            int pl = wv * 4 + pr * 2 + pt2;
            int pglob = p0 + pl;
            float res[4];
#pragma unroll
            for (int nt = 0; nt < 4; ++nt) {
                float base = baseS[pl * 68 + nt * 16 + col];
                f32x4 a = acc[pt2][nt];
                float v0 = fmaf(base + a[0], scv[nt], bov[nt]);
                float v1 = fmaf(base + a[1], scv[nt], bov[nt]);
                float v2 = fmaf(base + a[2], scv[nt], bov[nt]);
                float v3 = fmaf(base + a[3], scv[nt], bov[nt]);
                float vm = fmaxf(fmaxf(v0, v1), fmaxf(v2, v3));
                vm = fmaxf(vm, __shfl_xor(vm, 16));
                vm = fmaxf(vm, __shfl_xor(vm, 32));
                res[nt] = fmaxf(vm, 0.0f);
            }
            float rv = res[quad];
            hout[(size_t)pglob * Hh + lane] = rv;
            short hs_, ms_, ls_;
            split3(rv, hs_, ms_, ls_);
            hSout[0 * PLN + (size_t)pglob * Hh + lane] = hs_;
            hSout[1 * PLN + (size_t)pglob * Hh + lane] = ms_;
            hSout[2 * PLN + (size_t)pglob * Hh + lane] = ls_;

            float s = res[0] * res[0] + res[1] * res[1]
                    + res[2] * res[2] + res[3] * res[3];
            s += __shfl_xor(s, 1);
            s += __shfl_xor(s, 2);
            s += __shfl_xor(s, 4);
            s += __shfl_xor(s, 8);
            if (lane == 0) sqout[pglob] = s;
        }
    }
}

// ---------------------------------------------------------------------------
// head (unchanged)
// ---------------------------------------------------------------------------
__global__ __launch_bounds__(256) void k_head(
    const float* __restrict__ h,
    const float* __restrict__ w1, const float* __restrict__ g1, const float* __restrict__ b1,
    const float* __restrict__ w2, const float* __restrict__ b2,
    float* __restrict__ out)
{
    __shared__ float hcS[4][64];
    int t = threadIdx.x;
    int grp = t >> 6, o = t & 63;
    int p = blockIdx.x * 4 + grp;

    hcS[grp][o] = h[(size_t)p * Hh + o];
    __syncthreads();

    const float inv = rsqrtf(1.0f + EPSf);
    float acc = 0.0f;
#pragma unroll 8
    for (int c = 0; c < Hh; ++c)
        acc = fmaf(w1[o * Hh + c], hcS[grp][c], acc);
    acc = fmaxf(fmaf(acc, g1[o] * inv, b1[o]), 0.0f);

    float v = acc * w2[o];
#pragma unroll
    for (int off = 32; off > 0; off >>= 1) v += __shfl_down(v, off, 64);
    if (o == 0) out[p] = v + b2[0];
}

// ---------------------------------------------------------------------------
extern "C" void kernel_launch(void* const* d_in, const int* in_sizes, int n_in,
                              void* d_out, int out_size, void* d_ws, size_t ws_size,
                              hipStream_t stream)
{
    const float* x    = (const float*)d_in[0];
    const float* w_t1 = (const float*)d_in[1];
    const float* g_t1 = (const float*)d_in[2];
    const float* b_t1 = (const float*)d_in[3];
    const float* w_t2 = (const float*)d_in[4];
    const float* g_t2 = (const float*)d_in[5];
    const float* b_t2 = (const float*)d_in[6];
    const float* w_nb = (const float*)d_in[7];
    const float* g_nb = (const float*)d_in[8];
    const float* b_nb = (const float*)d_in[9];
    const float* w_s1 = (const float*)d_in[10];
    const float* g_s1 = (const float*)d_in[11];
    const float* b_s1 = (const float*)d_in[12];
    const float* w_s2 = (const float*)d_in[13];
    const float* b_s2 = (const float*)d_in[14];
    float* out = (float*)d_out;

    float* hA  = (float*)d_ws;
    float* hB  = hA + PLN;
    float* sq  = hB + PLN;
    int*   idx = (int*)(sq + (size_t)Bn * Nn);
    short* hSa = (short*)(idx + (size_t)Bn * Nn * Kk);
    short* hSb = hSa + 3 * PLN;
    short* wS  = hSb + 3 * PLN;

    k_prep<<<32, 256, 0, stream>>>(w_nb, wS);
    k_t12<<<Bn * Nn / 4, 256, 0, stream>>>(x, w_t1, g_t1, b_t1, w_t2, g_t2, b_t2,
                                           hA, hSa, sq);

    const float* hin = hA;
    float* hout = hB;
    const short* hSin = hSa;
    short* hSout = hSb;
    for (int r = 0; r < Rr; ++r) {
        k_knn<<<Bn * (Nn / 16), 256, 0, stream>>>(hin, sq, idx);
        k_edge<<<Bn * Nn / 16, 256, 0, stream>>>(hin, hSin, idx,
            wS + (size_t)r * 6 * 4096, g_nb + r * Hh, b_nb + r * Hh,
            hout, hSout, sq);
        const float* tf = hout; hout = (float*)hin; hin = tf;
        const short* ts = hSout; hSout = (short*)hSin; hSin = ts;
    }
    k_head<<<Bn * Nn / 4, 256, 0, stream>>>(hin, w_s1, g_s1, b_s1, w_s2, b_s2, out);
}

// Round 7
// 799.252 us; speedup vs baseline: 1.1413x; 1.1413x over previous
//
#include <hip/hip_runtime.h>
#include <math.h>

#define Bn 128
#define Nn 512
#define Cc 7
#define Hh 64
#define Kk 16
#define Rr 2
#define EPSf 1e-5f

typedef __attribute__((ext_vector_type(8))) short bf16x8;
typedef __attribute__((ext_vector_type(4))) float f32x4;

#define PLN ((size_t)4194304)   // elements per h-split plane (B*N*H)

// exact truncation split: a = hi + mid + lo + r, |r| <= 2^-24 |a|
__device__ __forceinline__ void split3(float a, short &hs, short &ms, short &ls) {
    unsigned u  = __float_as_uint(a);
    unsigned hu = u & 0xFFFF0000u;
    float r1 = a - __uint_as_float(hu);
    unsigned mu = __float_as_uint(r1) & 0xFFFF0000u;
    float r2 = r1 - __uint_as_float(mu);
    unsigned lu = __float_as_uint(r2) & 0xFFFF0000u;
    hs = (short)(hu >> 16); ms = (short)(mu >> 16); ls = (short)(lu >> 16);
}

#define MFMA6(acc, AH, AM, AL, BH, BM, BL) \
    acc = __builtin_amdgcn_mfma_f32_16x16x32_bf16(AL, BH, acc, 0, 0, 0); \
    acc = __builtin_amdgcn_mfma_f32_16x16x32_bf16(AM, BM, acc, 0, 0, 0); \
    acc = __builtin_amdgcn_mfma_f32_16x16x32_bf16(AH, BL, acc, 0, 0, 0); \
    acc = __builtin_amdgcn_mfma_f32_16x16x32_bf16(AM, BH, acc, 0, 0, 0); \
    acc = __builtin_amdgcn_mfma_f32_16x16x32_bf16(AH, BM, acc, 0, 0, 0); \
    acc = __builtin_amdgcn_mfma_f32_16x16x32_bf16(AH, BH, acc, 0, 0, 0);

// ---------------------------------------------------------------------------
// prep: split W per round into Wd (bf16x3) and Wc-Wd (bf16x3) planes.
// ---------------------------------------------------------------------------
__global__ void k_prep(const float* __restrict__ w_nb, short* __restrict__ wS)
{
    int i = blockIdx.x * 256 + threadIdx.x;     // 0 .. 2*64*64-1
    int r = i >> 12, oc = i & 4095;
    int o = oc >> 6, c = oc & 63;
    const float* wr = w_nb + (size_t)r * Hh * 2 * Hh + (size_t)o * 2 * Hh;
    float wc = wr[c], wd = wr[Hh + c];
    short* base = wS + (size_t)r * 6 * 4096;
    short h_, m_, l_;
    split3(wd, h_, m_, l_);
    base[0 * 4096 + oc] = h_; base[1 * 4096 + oc] = m_; base[2 * 4096 + oc] = l_;
    split3(wc - wd, h_, m_, l_);
    base[3 * 4096 + oc] = h_; base[4 * 4096 + oc] = m_; base[5 * 4096 + oc] = l_;
}

// ---------------------------------------------------------------------------
// t1 + t2 fused (h values bit-identical to prior rounds) + split-plane output
// ---------------------------------------------------------------------------
__global__ __launch_bounds__(256) void k_t12(
    const float* __restrict__ x,
    const float* __restrict__ w1, const float* __restrict__ g1, const float* __restrict__ b1,
    const float* __restrict__ w2, const float* __restrict__ g2, const float* __restrict__ b2,
    float* __restrict__ h, short* __restrict__ hS, float* __restrict__ sq)
{
    int t = threadIdx.x;
    int grp = t >> 6, o = t & 63;
    int p = blockIdx.x * 4 + grp;
    int b = p >> 9, n = p & 511;

    __shared__ float h1s[4][64];
    const float inv = rsqrtf(1.0f + EPSf);

    float acc = 0.0f;
#pragma unroll
    for (int c = 0; c < Cc; ++c)
        acc = fmaf(w1[o * Cc + c], x[(b * Cc + c) * Nn + n], acc);
    acc = fmaf(acc, g1[o] * inv, b1[o]);
    acc = fmaxf(acc, 0.0f);
    h1s[grp][o] = acc;
    __syncthreads();

    float a2 = 0.0f;
#pragma unroll 8
    for (int c = 0; c < Hh; ++c)
        a2 = fmaf(w2[o * Hh + c], h1s[grp][c], a2);
    a2 = fmaf(a2, g2[o] * inv, b2[o]);
    a2 = fmaxf(a2, 0.0f);
    h[(size_t)p * Hh + o] = a2;
    short hs_, ms_, ls_;
    split3(a2, hs_, ms_, ls_);
    hS[0 * PLN + (size_t)p * Hh + o] = hs_;
    hS[1 * PLN + (size_t)p * Hh + o] = ms_;
    hS[2 * PLN + (size_t)p * Hh + o] = ls_;

    float s = a2 * a2;
#pragma unroll
    for (int off = 32; off > 0; off >>= 1) s += __shfl_down(s, off, 64);
    if (o == 0) sq[p] = s;
}

// ---------------------------------------------------------------------------
// kNN: R3 structure (256 thr, 8 ctr, 2 pts/thread distance, 2 chains/wave
// selection) with DPP-accelerated min-reduce (quad_perm xor1/xor2 +
// row_ror 4/8 on VALU pipe; only xor16/xor32 on DS pipe).
// Distance expression textually identical to rounds 2-6 -> bit-identical keys.
// ---------------------------------------------------------------------------
__global__ __launch_bounds__(256) void k_knn(
    const float* __restrict__ h, const float* __restrict__ sq, int* __restrict__ idxout)
{
    int bidx = blockIdx.x;
    int b  = bidx >> 6;
    int n0 = (bidx & 63) << 3;
    int t  = threadIdx.x;

    __shared__ float4 ctr4[8 * 16];
    __shared__ unsigned int keysLDS[8 * 512];
    __shared__ float sqc[8];

    const float* hb = h + (size_t)b * Nn * Hh;
    float* ctr = (float*)ctr4;
    for (int i = t; i < 8 * Hh; i += 256) ctr[i] = hb[(size_t)n0 * Hh + i];
    if (t < 8) sqc[t] = sq[b * Nn + n0 + t];
    __syncthreads();

    {
        int m  = t;
        int m2 = t + 256;
        const float4* hv  = (const float4*)(hb + (size_t)m  * Hh);
        const float4* hv2 = (const float4*)(hb + (size_t)m2 * Hh);
        float dj[8], ej[8];
#pragma unroll
        for (int j = 0; j < 8; ++j) { dj[j] = 0.0f; ej[j] = 0.0f; }
#pragma unroll
        for (int c4 = 0; c4 < 16; ++c4) {
            float4 v  = hv[c4];
            float4 v2 = hv2[c4];
#pragma unroll
            for (int j = 0; j < 8; ++j) {
                float4 cv = ctr4[j * 16 + c4];
                dj[j] += v.x  * cv.x + v.y  * cv.y + v.z  * cv.z + v.w  * cv.w;
                ej[j] += v2.x * cv.x + v2.y * cv.y + v2.z * cv.z + v2.w * cv.w;
            }
        }
        float sm  = sq[b * Nn + m];
        float sm2 = sq[b * Nn + m2];
#pragma unroll
        for (int j = 0; j < 8; ++j) {
            float d = sqc[j] + sm - 2.0f * dj[j];
            unsigned int u = __float_as_uint(d);
            u = ((int)u < 0) ? ~u : (u | 0x80000000u);
            keysLDS[j * 512 + m] = u;

            float d2 = sqc[j] + sm2 - 2.0f * ej[j];
            unsigned int u2 = __float_as_uint(d2);
            u2 = ((int)u2 < 0) ? ~u2 : (u2 | 0x80000000u);
            keysLDS[j * 512 + m2] = u2;
        }
    }
    __syncthreads();

    int wvid = t >> 6, lane = t & 63;
    int j0 = wvid * 2, j1 = wvid * 2 + 1;

    unsigned int k0[8], k1[8];
    int r0[8], r1[8];
    {
        const uint4* kp0 = (const uint4*)&keysLDS[j0 * 512 + (lane << 3)];
        const uint4* kp1 = (const uint4*)&keysLDS[j1 * 512 + (lane << 3)];
        uint4 A = kp0[0], Bq = kp0[1];
        k0[0] = A.x;  k0[1] = A.y;  k0[2] = A.z;  k0[3] = A.w;
        k0[4] = Bq.x; k0[5] = Bq.y; k0[6] = Bq.z; k0[7] = Bq.w;
        uint4 C = kp1[0], D = kp1[1];
        k1[0] = C.x;  k1[1] = C.y;  k1[2] = C.z;  k1[3] = C.w;
        k1[4] = D.x;  k1[5] = D.y;  k1[6] = D.z;  k1[7] = D.w;
    }
#pragma unroll
    for (int q = 0; q < 8; ++q) { r0[q] = q; r1[q] = q; }

#define CE(kk, rr, i, j_) { \
    bool sw = (kk[i] > kk[j_]) || (kk[i] == kk[j_] && rr[i] > rr[j_]); \
    unsigned int tk = sw ? kk[i] : kk[j_]; kk[i] = sw ? kk[j_] : kk[i]; kk[j_] = tk; \
    int tr = sw ? rr[i] : rr[j_]; rr[i] = sw ? rr[j_] : rr[i]; rr[j_] = tr; }
#define SORT8(kk, rr) \
    CE(kk,rr,0,1) CE(kk,rr,2,3) CE(kk,rr,4,5) CE(kk,rr,6,7) \
    CE(kk,rr,0,2) CE(kk,rr,1,3) CE(kk,rr,4,6) CE(kk,rr,5,7) \
    CE(kk,rr,1,2) CE(kk,rr,5,6) \
    CE(kk,rr,0,4) CE(kk,rr,1,5) CE(kk,rr,2,6) CE(kk,rr,3,7) \
    CE(kk,rr,2,4) CE(kk,rr,3,5) \
    CE(kk,rr,1,2) CE(kk,rr,3,4) CE(kk,rr,5,6)

    SORT8(k0, r0)
    SORT8(k1, r1)
#undef SORT8
#undef CE

    int outbase0 = (b * Nn + n0 + j0) * Kk;
    int outbase1 = (b * Nn + n0 + j1) * Kk;

    for (int iter = 0; iter < Kk; ++iter) {
        unsigned int m0 = k0[0];
        unsigned int m1 = k1[0];
        // all-reduce min over 64 lanes: DPP (VALU) for 1,2,4,8; DS for 16,32
#define DSTEP(ctrl) { \
        unsigned int o0 = (unsigned int)__builtin_amdgcn_update_dpp((int)m0, (int)m0, ctrl, 0xF, 0xF, false); \
        unsigned int o1 = (unsigned int)__builtin_amdgcn_update_dpp((int)m1, (int)m1, ctrl, 0xF, 0xF, false); \
        m0 = (o0 < m0) ? o0 : m0; m1 = (o1 < m1) ? o1 : m1; }
        DSTEP(0xB1)   // quad_perm [1,0,3,2]  : xor 1
        DSTEP(0x4E)   // quad_perm [2,3,0,1]  : xor 2
        DSTEP(0x124)  // row_ror:4            : quads uniform -> +next quad
        DSTEP(0x128)  // row_ror:8            : row16 uniform
#undef DSTEP
        {
            unsigned int o0 = (unsigned int)__builtin_amdgcn_ds_swizzle((int)m0, 0x401F); // xor 16
            unsigned int o1 = (unsigned int)__builtin_amdgcn_ds_swizzle((int)m1, 0x401F);
            m0 = (o0 < m0) ? o0 : m0; m1 = (o1 < m1) ? o1 : m1;
        }
        {
            unsigned int o0 = __shfl_xor(m0, 32, 64);
            unsigned int o1 = __shfl_xor(m1, 32, 64);
            m0 = (o0 < m0) ? o0 : m0; m1 = (o1 < m1) ? o1 : m1;
        }
        unsigned long long bal0 = __ballot(k0[0] == m0);
        unsigned long long bal1 = __ballot(k1[0] == m1);
        int w0 = __ffsll(bal0) - 1;
        int w1 = __ffsll(bal1) - 1;
        if (lane == w0) {
            idxout[outbase0 + iter] = (lane << 3) + r0[0];
#pragma unroll
            for (int q = 0; q < 7; ++q) { k0[q] = k0[q + 1]; r0[q] = r0[q + 1]; }
            k0[7] = 0xFFFFFFFFu;
        }
        if (lane == w1) {
            idxout[outbase1 + iter] = (lane << 3) + r1[0];
#pragma unroll
            for (int q = 0; q < 7; ++q) { k1[q] = k1[q + 1]; r1[q] = r1[q + 1]; }
            k1[7] = 0xFFFFFFFFu;
        }
    }
}

// ---------------------------------------------------------------------------
// EdgeConv via MFMA, base/delta decomposition. W LDS region is staged TWICE
// (wcd for base phase, then overwritten with wd for the neighbor loop) to
// halve LDS -> 4 blocks/CU. Arithmetic bit-identical to rounds 5/6.
// ---------------------------------------------------------------------------
__global__ __launch_bounds__(256, 4) void k_edge(
    const float* __restrict__ h, const short* __restrict__ hS,
    const int* __restrict__ idx,
    const short* __restrict__ wS,
    const float* __restrict__ g, const float* __restrict__ bb_,
    float* __restrict__ hout, short* __restrict__ hSout, float* __restrict__ sqout)
{
    __shared__ short wLDS[3][64 * 72];
    __shared__ float baseS[16 * 68];
    __shared__ int   idxS[256];

    int t  = threadIdx.x;
    int p0 = blockIdx.x * 16;
    int b  = p0 >> 9;

    idxS[t] = idx[p0 * Kk + t];
    // ---- stage wcd splits (planes 3..5) ----
#pragma unroll
    for (int it = 0; it < 6; ++it) {
        int f = it * 256 + t;              // uint4 index 0..1535
        int plane = f >> 9;                // 0..2
        int i8 = f & 511;
        int o = i8 >> 3, c8 = i8 & 7;
        uint4 v = ((const uint4*)(wS + (size_t)(3 + plane) * 4096))[i8];
        *(uint4*)&wLDS[plane][o * 72 + c8 * 8] = v;
    }
    __syncthreads();

    int wv = t >> 6, lane = t & 63, col = lane & 15, quad = lane >> 4;

    // ---- base phase: wave wv computes nt=wv tile of base[16 pts][16 o] ----
    {
        f32x4 bacc = (f32x4){0.f, 0.f, 0.f, 0.f};
        const short* hrow = hS + (size_t)(p0 + col) * Hh;
#pragma unroll
        for (int ks = 0; ks < 2; ++ks) {
            int aoff = ks * 32 + quad * 8;
            bf16x8 AH = *(const bf16x8*)(hrow + 0 * PLN + aoff);
            bf16x8 AM = *(const bf16x8*)(hrow + 1 * PLN + aoff);
            bf16x8 AL = *(const bf16x8*)(hrow + 2 * PLN + aoff);
            int boff = (wv * 16 + col) * 72 + aoff;
            bf16x8 BH = *(bf16x8*)&wLDS[0][boff];
            bf16x8 BM = *(bf16x8*)&wLDS[1][boff];
            bf16x8 BL = *(bf16x8*)&wLDS[2][boff];
            MFMA6(bacc, AH, AM, AL, BH, BM, BL)
        }
#pragma unroll
        for (int r_ = 0; r_ < 4; ++r_)
            baseS[(quad * 4 + r_) * 68 + wv * 16 + col] = bacc[r_];
    }
    __syncthreads();

    // ---- overwrite with wd splits (planes 0..2) ----
#pragma unroll
    for (int it = 0; it < 6; ++it) {
        int f = it * 256 + t;
        int plane = f >> 9;
        int i8 = f & 511;
        int o = i8 >> 3, c8 = i8 & 7;
        uint4 v = ((const uint4*)(wS + (size_t)plane * 4096))[i8];
        *(uint4*)&wLDS[plane][o * 72 + c8 * 8] = v;
    }
    __syncthreads();

    const float inv = rsqrtf(1.0f + EPSf);
    float scv[4], bov[4];
#pragma unroll
    for (int nt = 0; nt < 4; ++nt) {
        scv[nt] = g[nt * 16 + col] * inv;
        bov[nt] = bb_[nt * 16 + col];
    }

    for (int pr = 0; pr < 2; ++pr) {
        bf16x8 A[2][2][3];
#pragma unroll
        for (int pt2 = 0; pt2 < 2; ++pt2) {
            int pl = wv * 4 + pr * 2 + pt2;
            int j = idxS[pl * 16 + col];
            const short* nrow = hS + ((size_t)(b * Nn) + j) * Hh;
#pragma unroll
            for (int ks = 0; ks < 2; ++ks) {
                int aoff = ks * 32 + quad * 8;
                A[pt2][ks][0] = *(const bf16x8*)(nrow + 0 * PLN + aoff);
                A[pt2][ks][1] = *(const bf16x8*)(nrow + 1 * PLN + aoff);
                A[pt2][ks][2] = *(const bf16x8*)(nrow + 2 * PLN + aoff);
            }
        }

        f32x4 acc[2][4];
#pragma unroll
        for (int pt2 = 0; pt2 < 2; ++pt2)
#pragma unroll
            for (int nt = 0; nt < 4; ++nt)
                acc[pt2][nt] = (f32x4){0.f, 0.f, 0.f, 0.f};

#pragma unroll
        for (int ks = 0; ks < 2; ++ks)
#pragma unroll
            for (int nt = 0; nt < 4; ++nt) {
                int boff = (nt * 16 + col) * 72 + ks * 32 + quad * 8;
                bf16x8 BH = *(bf16x8*)&wLDS[0][boff];
                bf16x8 BM = *(bf16x8*)&wLDS[1][boff];
                bf16x8 BL = *(bf16x8*)&wLDS[2][boff];
#pragma unroll
                for (int pt2 = 0; pt2 < 2; ++pt2) {
                    f32x4 a = acc[pt2][nt];
                    MFMA6(a, A[pt2][ks][0], A[pt2][ks][1], A[pt2][ks][2], BH, BM, BL)
                    acc[pt2][nt] = a;
                }
            }

        // epilogue: m = base + delta; bn per-k; max over k; relu
#pragma unroll
        for (int pt2 = 0; pt2 < 2; ++pt2) {
            int pl = wv * 4 + pr * 2 + pt2;
            int pglob = p0 + pl;
            float res[4];
#pragma unroll
            for (int nt = 0; nt < 4; ++nt) {
                float base = baseS[pl * 68 + nt * 16 + col];
                f32x4 a = acc[pt2][nt];
                float v0 = fmaf(base + a[0], scv[nt], bov[nt]);
                float v1 = fmaf(base + a[1], scv[nt], bov[nt]);
                float v2 = fmaf(base + a[2], scv[nt], bov[nt]);
                float v3 = fmaf(base + a[3], scv[nt], bov[nt]);
                float vm = fmaxf(fmaxf(v0, v1), fmaxf(v2, v3));
                vm = fmaxf(vm, __shfl_xor(vm, 16));
                vm = fmaxf(vm, __shfl_xor(vm, 32));
                res[nt] = fmaxf(vm, 0.0f);
            }
            float rv = res[quad];
            hout[(size_t)pglob * Hh + lane] = rv;
            short hs_, ms_, ls_;
            split3(rv, hs_, ms_, ls_);
            hSout[0 * PLN + (size_t)pglob * Hh + lane] = hs_;
            hSout[1 * PLN + (size_t)pglob * Hh + lane] = ms_;
            hSout[2 * PLN + (size_t)pglob * Hh + lane] = ls_;

            float s = res[0] * res[0] + res[1] * res[1]
                    + res[2] * res[2] + res[3] * res[3];
            s += __shfl_xor(s, 1);
            s += __shfl_xor(s, 2);
            s += __shfl_xor(s, 4);
            s += __shfl_xor(s, 8);
            if (lane == 0) sqout[pglob] = s;
        }
    }
}

// ---------------------------------------------------------------------------
// head (unchanged)
// ---------------------------------------------------------------------------
__global__ __launch_bounds__(256) void k_head(
    const float* __restrict__ h,
    const float* __restrict__ w1, const float* __restrict__ g1, const float* __restrict__ b1,
    const float* __restrict__ w2, const float* __restrict__ b2,
    float* __restrict__ out)
{
    __shared__ float hcS[4][64];
    int t = threadIdx.x;
    int grp = t >> 6, o = t & 63;
    int p = blockIdx.x * 4 + grp;

    hcS[grp][o] = h[(size_t)p * Hh + o];
    __syncthreads();

    const float inv = rsqrtf(1.0f + EPSf);
    float acc = 0.0f;
#pragma unroll 8
    for (int c = 0; c < Hh; ++c)
        acc = fmaf(w1[o * Hh + c], hcS[grp][c], acc);
    acc = fmaxf(fmaf(acc, g1[o] * inv, b1[o]), 0.0f);

    float v = acc * w2[o];
#pragma unroll
    for (int off = 32; off > 0; off >>= 1) v += __shfl_down(v, off, 64);
    if (o == 0) out[p] = v + b2[0];
}

// ---------------------------------------------------------------------------
extern "C" void kernel_launch(void* const* d_in, const int* in_sizes, int n_in,
                              void* d_out, int out_size, void* d_ws, size_t ws_size,
                              hipStream_t stream)
{
    const float* x    = (const float*)d_in[0];
    const float* w_t1 = (const float*)d_in[1];
    const float* g_t1 = (const float*)d_in[2];
    const float* b_t1 = (const float*)d_in[3];
    const float* w_t2 = (const float*)d_in[4];
    const float* g_t2 = (const float*)d_in[5];
    const float* b_t2 = (const float*)d_in[6];
    const float* w_nb = (const float*)d_in[7];
    const float* g_nb = (const float*)d_in[8];
    const float* b_nb = (const float*)d_in[9];
    const float* w_s1 = (const float*)d_in[10];
    const float* g_s1 = (const float*)d_in[11];
    const float* b_s1 = (const float*)d_in[12];
    const float* w_s2 = (const float*)d_in[13];
    const float* b_s2 = (const float*)d_in[14];
    float* out = (float*)d_out;

    float* hA  = (float*)d_ws;
    float* hB  = hA + PLN;
    float* sq  = hB + PLN;
    int*   idx = (int*)(sq + (size_t)Bn * Nn);
    short* hSa = (short*)(idx + (size_t)Bn * Nn * Kk);
    short* hSb = hSa + 3 * PLN;
    short* wS  = hSb + 3 * PLN;

    k_prep<<<32, 256, 0, stream>>>(w_nb, wS);
    k_t12<<<Bn * Nn / 4, 256, 0, stream>>>(x, w_t1, g_t1, b_t1, w_t2, g_t2, b_t2,
                                           hA, hSa, sq);

    const float* hin = hA;
    float* hout = hB;
    const short* hSin = hSa;
    short* hSout = hSb;
    for (int r = 0; r < Rr; ++r) {
        k_knn<<<Bn * (Nn / 8), 256, 0, stream>>>(hin, sq, idx);
        k_edge<<<Bn * Nn / 16, 256, 0, stream>>>(hin, hSin, idx,
            wS + (size_t)r * 6 * 4096, g_nb + r * Hh, b_nb + r * Hh,
            hout, hSout, sq);
        const float* tf = hout; hout = (float*)hin; hin = tf;
        const short* ts = hSout; hSout = (short*)hSin; hSin = ts;
    }
    k_head<<<Bn * Nn / 4, 256, 0, stream>>>(hin, w_s1, g_s1, b_s1, w_s2, b_s2, out);
}

// Round 8
// 693.894 us; speedup vs baseline: 1.3146x; 1.1518x over previous
//
#include <hip/hip_runtime.h>
#include <math.h>

#define Bn 128
#define Nn 512
#define Cc 7
#define Hh 64
#define Kk 16
#define Rr 2
#define EPSf 1e-5f

typedef __attribute__((ext_vector_type(8))) short bf16x8;
typedef __attribute__((ext_vector_type(4))) float f32x4;

#define PLN ((size_t)4194304)   // elements per h-split plane (B*N*H)

// exact truncation split: a = hi + mid + lo + r, |r| <= 2^-24 |a|
__device__ __forceinline__ void split3(float a, short &hs, short &ms, short &ls) {
    unsigned u  = __float_as_uint(a);
    unsigned hu = u & 0xFFFF0000u;
    float r1 = a - __uint_as_float(hu);
    unsigned mu = __float_as_uint(r1) & 0xFFFF0000u;
    float r2 = r1 - __uint_as_float(mu);
    unsigned lu = __float_as_uint(r2) & 0xFFFF0000u;
    hs = (short)(hu >> 16); ms = (short)(mu >> 16); ls = (short)(lu >> 16);
}

#define MFMA6(acc, AH, AM, AL, BH, BM, BL) \
    acc = __builtin_amdgcn_mfma_f32_16x16x32_bf16(AL, BH, acc, 0, 0, 0); \
    acc = __builtin_amdgcn_mfma_f32_16x16x32_bf16(AM, BM, acc, 0, 0, 0); \
    acc = __builtin_amdgcn_mfma_f32_16x16x32_bf16(AH, BL, acc, 0, 0, 0); \
    acc = __builtin_amdgcn_mfma_f32_16x16x32_bf16(AM, BH, acc, 0, 0, 0); \
    acc = __builtin_amdgcn_mfma_f32_16x16x32_bf16(AH, BM, acc, 0, 0, 0); \
    acc = __builtin_amdgcn_mfma_f32_16x16x32_bf16(AH, BH, acc, 0, 0, 0);

// ---------------------------------------------------------------------------
// prep: split W per round into Wd (bf16x3) and Wc-Wd (bf16x3) planes.
// ---------------------------------------------------------------------------
__global__ void k_prep(const float* __restrict__ w_nb, short* __restrict__ wS)
{
    int i = blockIdx.x * 256 + threadIdx.x;     // 0 .. 2*64*64-1
    int r = i >> 12, oc = i & 4095;
    int o = oc >> 6, c = oc & 63;
    const float* wr = w_nb + (size_t)r * Hh * 2 * Hh + (size_t)o * 2 * Hh;
    float wc = wr[c], wd = wr[Hh + c];
    short* base = wS + (size_t)r * 6 * 4096;
    short h_, m_, l_;
    split3(wd, h_, m_, l_);
    base[0 * 4096 + oc] = h_; base[1 * 4096 + oc] = m_; base[2 * 4096 + oc] = l_;
    split3(wc - wd, h_, m_, l_);
    base[3 * 4096 + oc] = h_; base[4 * 4096 + oc] = m_; base[5 * 4096 + oc] = l_;
}

// ---------------------------------------------------------------------------
// t1 + t2 fused + split-plane output
// ---------------------------------------------------------------------------
__global__ __launch_bounds__(256) void k_t12(
    const float* __restrict__ x,
    const float* __restrict__ w1, const float* __restrict__ g1, const float* __restrict__ b1,
    const float* __restrict__ w2, const float* __restrict__ g2, const float* __restrict__ b2,
    float* __restrict__ h, short* __restrict__ hS, float* __restrict__ sq)
{
    int t = threadIdx.x;
    int grp = t >> 6, o = t & 63;
    int p = blockIdx.x * 4 + grp;
    int b = p >> 9, n = p & 511;

    __shared__ float h1s[4][64];
    const float inv = rsqrtf(1.0f + EPSf);

    float acc = 0.0f;
#pragma unroll
    for (int c = 0; c < Cc; ++c)
        acc = fmaf(w1[o * Cc + c], x[(b * Cc + c) * Nn + n], acc);
    acc = fmaf(acc, g1[o] * inv, b1[o]);
    acc = fmaxf(acc, 0.0f);
    h1s[grp][o] = acc;
    __syncthreads();

    float a2 = 0.0f;
#pragma unroll 8
    for (int c = 0; c < Hh; ++c)
        a2 = fmaf(w2[o * Hh + c], h1s[grp][c], a2);
    a2 = fmaf(a2, g2[o] * inv, b2[o]);
    a2 = fmaxf(a2, 0.0f);
    h[(size_t)p * Hh + o] = a2;
    short hs_, ms_, ls_;
    split3(a2, hs_, ms_, ls_);
    hS[0 * PLN + (size_t)p * Hh + o] = hs_;
    hS[1 * PLN + (size_t)p * Hh + o] = ms_;
    hS[2 * PLN + (size_t)p * Hh + o] = ls_;

    float s = a2 * a2;
#pragma unroll
    for (int off = 32; off > 0; off >>= 1) s += __shfl_down(s, off, 64);
    if (o == 0) sq[p] = s;
}

// ---------------------------------------------------------------------------
// kNN: Gram matrix via MFMA (bf16x3 split, 6 products — same error class as
// k_edge). Block = 16 centers x 512 points of one batch. Keys layout and
// selection (4 chains/wave, DPP min-reduce, ballot-ffs lane-major tie-break)
// identical to proven rounds 6/7.
// ---------------------------------------------------------------------------
__global__ __launch_bounds__(256) void k_knn(
    const short* __restrict__ hS, const float* __restrict__ sq, int* __restrict__ idxout)
{
    int bidx = blockIdx.x;
    int b  = bidx >> 5;                    // 32 center-strips per batch
    int n0 = (bidx & 31) << 4;             // 16 centers
    int t  = threadIdx.x;

    __shared__ unsigned int keysLDS[16 * 512];   // 32 KB
    __shared__ float sqS[512];

    // stage sq for the whole batch
    if (t < 128) ((float4*)sqS)[t] = ((const float4*)(sq + (size_t)b * Nn))[t];
    __syncthreads();

    int wv = t >> 6, lane = t & 63, col = lane & 15, quad = lane >> 4;
    const size_t rowbase = (size_t)b * Nn * Hh;

    // ---- A-frags: the 16 center rows (shared by all waves) ----
    bf16x8 AH[2], AM[2], AL[2];
    {
        const short* crow = hS + rowbase + (size_t)(n0 + col) * Hh;
#pragma unroll
        for (int ks = 0; ks < 2; ++ks) {
            int aoff = ks * 32 + quad * 8;
            AH[ks] = *(const bf16x8*)(crow + 0 * PLN + aoff);
            AM[ks] = *(const bf16x8*)(crow + 1 * PLN + aoff);
            AL[ks] = *(const bf16x8*)(crow + 2 * PLN + aoff);
        }
    }
    float sqcr[4];
#pragma unroll
    for (int r_ = 0; r_ < 4; ++r_) sqcr[r_] = sqS[n0 + quad * 4 + r_];

    // ---- Gram tiles: wave wv handles n-tiles wv*8 .. wv*8+7 ----
    for (int i = 0; i < 8; ++i) {
        int nt = wv * 8 + i;
        const short* prow = hS + rowbase + (size_t)(nt * 16 + col) * Hh;
        f32x4 acc = (f32x4){0.f, 0.f, 0.f, 0.f};
#pragma unroll
        for (int ks = 0; ks < 2; ++ks) {
            int aoff = ks * 32 + quad * 8;
            bf16x8 BH = *(const bf16x8*)(prow + 0 * PLN + aoff);
            bf16x8 BM = *(const bf16x8*)(prow + 1 * PLN + aoff);
            bf16x8 BL = *(const bf16x8*)(prow + 2 * PLN + aoff);
            MFMA6(acc, AH[ks], AM[ks], AL[ks], BH, BM, BL)
        }
        // D: col (lane&15) = point, row (quad*4+reg) = center
        float sqp = sqS[nt * 16 + col];
#pragma unroll
        for (int r_ = 0; r_ < 4; ++r_) {
            int ctr = quad * 4 + r_;
            float d = sqcr[r_] + sqp - 2.0f * acc[r_];
            unsigned int u = __float_as_uint(d);
            u = ((int)u < 0) ? ~u : (u | 0x80000000u);
            keysLDS[ctr * 512 + nt * 16 + col] = u;
        }
    }
    __syncthreads();

    // ---- selection: wave wv handles centers wv*4 .. wv*4+3 concurrently ----
    unsigned int kk[4][8];
    int rr[4][8];
#pragma unroll
    for (int s = 0; s < 4; ++s) {
        int jj = wv * 4 + s;
        const uint4* kp = (const uint4*)&keysLDS[jj * 512 + (lane << 3)];
        uint4 A = kp[0], Bq = kp[1];
        kk[s][0] = A.x;  kk[s][1] = A.y;  kk[s][2] = A.z;  kk[s][3] = A.w;
        kk[s][4] = Bq.x; kk[s][5] = Bq.y; kk[s][6] = Bq.z; kk[s][7] = Bq.w;
#pragma unroll
        for (int q = 0; q < 8; ++q) rr[s][q] = q;
    }

#define CE(s, i, j_) { \
    bool sw = (kk[s][i] > kk[s][j_]) || (kk[s][i] == kk[s][j_] && rr[s][i] > rr[s][j_]); \
    unsigned int tk = sw ? kk[s][i] : kk[s][j_]; kk[s][i] = sw ? kk[s][j_] : kk[s][i]; kk[s][j_] = tk; \
    int tr = sw ? rr[s][i] : rr[s][j_]; rr[s][i] = sw ? rr[s][j_] : rr[s][i]; rr[s][j_] = tr; }
#pragma unroll
    for (int s = 0; s < 4; ++s) {
        CE(s,0,1) CE(s,2,3) CE(s,4,5) CE(s,6,7)
        CE(s,0,2) CE(s,1,3) CE(s,4,6) CE(s,5,7)
        CE(s,1,2) CE(s,5,6)
        CE(s,0,4) CE(s,1,5) CE(s,2,6) CE(s,3,7)
        CE(s,2,4) CE(s,3,5)
        CE(s,1,2) CE(s,3,4) CE(s,5,6)
    }
#undef CE

    int outbase[4];
#pragma unroll
    for (int s = 0; s < 4; ++s) outbase[s] = (b * Nn + n0 + wv * 4 + s) * Kk;

    for (int iter = 0; iter < Kk; ++iter) {
        unsigned int mv[4];
#pragma unroll
        for (int s = 0; s < 4; ++s) mv[s] = kk[s][0];
#define DSTEP(ctrl) { \
        _Pragma("unroll") \
        for (int s = 0; s < 4; ++s) { \
            unsigned int ov = (unsigned int)__builtin_amdgcn_update_dpp((int)mv[s], (int)mv[s], ctrl, 0xF, 0xF, false); \
            mv[s] = (ov < mv[s]) ? ov : mv[s]; } }
        DSTEP(0xB1)   // quad_perm xor1
        DSTEP(0x4E)   // quad_perm xor2
        DSTEP(0x124)  // row_ror:4
        DSTEP(0x128)  // row_ror:8
#undef DSTEP
#pragma unroll
        for (int s = 0; s < 4; ++s) {
            unsigned int ov = (unsigned int)__builtin_amdgcn_ds_swizzle((int)mv[s], 0x401F);
            mv[s] = (ov < mv[s]) ? ov : mv[s];
        }
#pragma unroll
        for (int s = 0; s < 4; ++s) {
            unsigned int ov = __shfl_xor(mv[s], 32, 64);
            mv[s] = (ov < mv[s]) ? ov : mv[s];
        }
#pragma unroll
        for (int s = 0; s < 4; ++s) {
            unsigned long long bal = __ballot(kk[s][0] == mv[s]);
            int wn = __ffsll(bal) - 1;
            if (lane == wn) {
                idxout[outbase[s] + iter] = (lane << 3) + rr[s][0];
#pragma unroll
                for (int q = 0; q < 7; ++q) { kk[s][q] = kk[s][q + 1]; rr[s][q] = rr[s][q + 1]; }
                kk[s][7] = 0xFFFFFFFFu;
            }
        }
    }
}

// ---------------------------------------------------------------------------
// EdgeConv via MFMA, base/delta decomposition (unchanged from round 7)
// ---------------------------------------------------------------------------
__global__ __launch_bounds__(256, 4) void k_edge(
    const float* __restrict__ h, const short* __restrict__ hS,
    const int* __restrict__ idx,
    const short* __restrict__ wS,
    const float* __restrict__ g, const float* __restrict__ bb_,
    float* __restrict__ hout, short* __restrict__ hSout, float* __restrict__ sqout)
{
    __shared__ short wLDS[3][64 * 72];
    __shared__ float baseS[16 * 68];
    __shared__ int   idxS[256];

    int t  = threadIdx.x;
    int p0 = blockIdx.x * 16;
    int b  = p0 >> 9;

    idxS[t] = idx[p0 * Kk + t];
#pragma unroll
    for (int it = 0; it < 6; ++it) {
        int f = it * 256 + t;
        int plane = f >> 9;
        int i8 = f & 511;
        int o = i8 >> 3, c8 = i8 & 7;
        uint4 v = ((const uint4*)(wS + (size_t)(3 + plane) * 4096))[i8];
        *(uint4*)&wLDS[plane][o * 72 + c8 * 8] = v;
    }
    __syncthreads();

    int wv = t >> 6, lane = t & 63, col = lane & 15, quad = lane >> 4;

    {
        f32x4 bacc = (f32x4){0.f, 0.f, 0.f, 0.f};
        const short* hrow = hS + (size_t)(p0 + col) * Hh;
#pragma unroll
        for (int ks = 0; ks < 2; ++ks) {
            int aoff = ks * 32 + quad * 8;
            bf16x8 AH = *(const bf16x8*)(hrow + 0 * PLN + aoff);
            bf16x8 AM = *(const bf16x8*)(hrow + 1 * PLN + aoff);
            bf16x8 AL = *(const bf16x8*)(hrow + 2 * PLN + aoff);
            int boff = (wv * 16 + col) * 72 + aoff;
            bf16x8 BH = *(bf16x8*)&wLDS[0][boff];
            bf16x8 BM = *(bf16x8*)&wLDS[1][boff];
            bf16x8 BL = *(bf16x8*)&wLDS[2][boff];
            MFMA6(bacc, AH, AM, AL, BH, BM, BL)
        }
#pragma unroll
        for (int r_ = 0; r_ < 4; ++r_)
            baseS[(quad * 4 + r_) * 68 + wv * 16 + col] = bacc[r_];
    }
    __syncthreads();

#pragma unroll
    for (int it = 0; it < 6; ++it) {
        int f = it * 256 + t;
        int plane = f >> 9;
        int i8 = f & 511;
        int o = i8 >> 3, c8 = i8 & 7;
        uint4 v = ((const uint4*)(wS + (size_t)plane * 4096))[i8];
        *(uint4*)&wLDS[plane][o * 72 + c8 * 8] = v;
    }
    __syncthreads();

    const float inv = rsqrtf(1.0f + EPSf);
    float scv[4], bov[4];
#pragma unroll
    for (int nt = 0; nt < 4; ++nt) {
        scv[nt] = g[nt * 16 + col] * inv;
        bov[nt] = bb_[nt * 16 + col];
    }

    for (int pr = 0; pr < 2; ++pr) {
        bf16x8 A[2][2][3];
#pragma unroll
        for (int pt2 = 0; pt2 < 2; ++pt2) {
            int pl = wv * 4 + pr * 2 + pt2;
            int j = idxS[pl * 16 + col];
            const short* nrow = hS + ((size_t)(b * Nn) + j) * Hh;
#pragma unroll
            for (int ks = 0; ks < 2; ++ks) {
                int aoff = ks * 32 + quad * 8;
                A[pt2][ks][0] = *(const bf16x8*)(nrow + 0 * PLN + aoff);
                A[pt2][ks][1] = *(const bf16x8*)(nrow + 1 * PLN + aoff);
                A[pt2][ks][2] = *(const bf16x8*)(nrow + 2 * PLN + aoff);
            }
        }

        f32x4 acc[2][4];
#pragma unroll
        for (int pt2 = 0; pt2 < 2; ++pt2)
#pragma unroll
            for (int nt = 0; nt < 4; ++nt)
                acc[pt2][nt] = (f32x4){0.f, 0.f, 0.f, 0.f};

#pragma unroll
        for (int ks = 0; ks < 2; ++ks)
#pragma unroll
            for (int nt = 0; nt < 4; ++nt) {
                int boff = (nt * 16 + col) * 72 + ks * 32 + quad * 8;
                bf16x8 BH = *(bf16x8*)&wLDS[0][boff];
                bf16x8 BM = *(bf16x8*)&wLDS[1][boff];
                bf16x8 BL = *(bf16x8*)&wLDS[2][boff];
#pragma unroll
                for (int pt2 = 0; pt2 < 2; ++pt2) {
                    f32x4 a = acc[pt2][nt];
                    MFMA6(a, A[pt2][ks][0], A[pt2][ks][1], A[pt2][ks][2], BH, BM, BL)
                    acc[pt2][nt] = a;
                }
            }

#pragma unroll
        for (int pt2 = 0; pt2 < 2; ++pt2) {
            int pl = wv * 4 + pr * 2 + pt2;
            int pglob = p0 + pl;
            float res[4];
#pragma unroll
            for (int nt = 0; nt < 4; ++nt) {
                float base = baseS[pl * 68 + nt * 16 + col];
                f32x4 a = acc[pt2][nt];
                float v0 = fmaf(base + a[0], scv[nt], bov[nt]);
                float v1 = fmaf(base + a[1], scv[nt], bov[nt]);
                float v2 = fmaf(base + a[2], scv[nt], bov[nt]);
                float v3 = fmaf(base + a[3], scv[nt], bov[nt]);
                float vm = fmaxf(fmaxf(v0, v1), fmaxf(v2, v3));
                vm = fmaxf(vm, __shfl_xor(vm, 16));
                vm = fmaxf(vm, __shfl_xor(vm, 32));
                res[nt] = fmaxf(vm, 0.0f);
            }
            float rv = res[quad];
            hout[(size_t)pglob * Hh + lane] = rv;
            short hs_, ms_, ls_;
            split3(rv, hs_, ms_, ls_);
            hSout[0 * PLN + (size_t)pglob * Hh + lane] = hs_;
            hSout[1 * PLN + (size_t)pglob * Hh + lane] = ms_;
            hSout[2 * PLN + (size_t)pglob * Hh + lane] = ls_;

            float s = res[0] * res[0] + res[1] * res[1]
                    + res[2] * res[2] + res[3] * res[3];
            s += __shfl_xor(s, 1);
            s += __shfl_xor(s, 2);
            s += __shfl_xor(s, 4);
            s += __shfl_xor(s, 8);
            if (lane == 0) sqout[pglob] = s;
        }
    }
}

// ---------------------------------------------------------------------------
// head (unchanged)
// ---------------------------------------------------------------------------
__global__ __launch_bounds__(256) void k_head(
    const float* __restrict__ h,
    const float* __restrict__ w1, const float* __restrict__ g1, const float* __restrict__ b1,
    const float* __restrict__ w2, const float* __restrict__ b2,
    float* __restrict__ out)
{
    __shared__ float hcS[4][64];
    int t = threadIdx.x;
    int grp = t >> 6, o = t & 63;
    int p = blockIdx.x * 4 + grp;

    hcS[grp][o] = h[(size_t)p * Hh + o];
    __syncthreads();

    const float inv = rsqrtf(1.0f + EPSf);
    float acc = 0.0f;
#pragma unroll 8
    for (int c = 0; c < Hh; ++c)
        acc = fmaf(w1[o * Hh + c], hcS[grp][c], acc);
    acc = fmaxf(fmaf(acc, g1[o] * inv, b1[o]), 0.0f);

    float v = acc * w2[o];
#pragma unroll
    for (int off = 32; off > 0; off >>= 1) v += __shfl_down(v, off, 64);
    if (o == 0) out[p] = v + b2[0];
}

// ---------------------------------------------------------------------------
extern "C" void kernel_launch(void* const* d_in, const int* in_sizes, int n_in,
                              void* d_out, int out_size, void* d_ws, size_t ws_size,
                              hipStream_t stream)
{
    const float* x    = (const float*)d_in[0];
    const float* w_t1 = (const float*)d_in[1];
    const float* g_t1 = (const float*)d_in[2];
    const float* b_t1 = (const float*)d_in[3];
    const float* w_t2 = (const float*)d_in[4];
    const float* g_t2 = (const float*)d_in[5];
    const float* b_t2 = (const float*)d_in[6];
    const float* w_nb = (const float*)d_in[7];
    const float* g_nb = (const float*)d_in[8];
    const float* b_nb = (const float*)d_in[9];
    const float* w_s1 = (const float*)d_in[10];
    const float* g_s1 = (const float*)d_in[11];
    const float* b_s1 = (const float*)d_in[12];
    const float* w_s2 = (const float*)d_in[13];
    const float* b_s2 = (const float*)d_in[14];
    float* out = (float*)d_out;

    float* hA  = (float*)d_ws;
    float* hB  = hA + PLN;
    float* sq  = hB + PLN;
    int*   idx = (int*)(sq + (size_t)Bn * Nn);
    short* hSa = (short*)(idx + (size_t)Bn * Nn * Kk);
    short* hSb = hSa + 3 * PLN;
    short* wS  = hSb + 3 * PLN;

    k_prep<<<32, 256, 0, stream>>>(w_nb, wS);
    k_t12<<<Bn * Nn / 4, 256, 0, stream>>>(x, w_t1, g_t1, b_t1, w_t2, g_t2, b_t2,
                                           hA, hSa, sq);

    const float* hin = hA;
    float* hout = hB;
    const short* hSin = hSa;
    short* hSout = hSb;
    for (int r = 0; r < Rr; ++r) {
        k_knn<<<Bn * (Nn / 16), 256, 0, stream>>>(hSin, sq, idx);
        k_edge<<<Bn * Nn / 16, 256, 0, stream>>>(hin, hSin, idx,
            wS + (size_t)r * 6 * 4096, g_nb + r * Hh, b_nb + r * Hh,
            hout, hSout, sq);
        const float* tf = hout; hout = (float*)hin; hin = tf;
        const short* ts = hSout; hSout = (short*)hSin; hSin = ts;
    }
    k_head<<<Bn * Nn / 4, 256, 0, stream>>>(hin, w_s1, g_s1, b_s1, w_s2, b_s2, out);
}

// Round 9
// 690.673 us; speedup vs baseline: 1.3208x; 1.0047x over previous
//
#include <hip/hip_runtime.h>
#include <math.h>

#define Bn 128
#define Nn 512
#define Cc 7
#define Hh 64
#define Kk 16
#define Rr 2
#define EPSf 1e-5f

typedef __attribute__((ext_vector_type(8))) short bf16x8;
typedef __attribute__((ext_vector_type(4))) float f32x4;

#define PLN ((size_t)4194304)   // elements per h-split plane (B*N*H)

// exact truncation split: a = hi + mid + lo + r, |r| <= 2^-24 |a|
__device__ __forceinline__ void split3(float a, short &hs, short &ms, short &ls) {
    unsigned u  = __float_as_uint(a);
    unsigned hu = u & 0xFFFF0000u;
    float r1 = a - __uint_as_float(hu);
    unsigned mu = __float_as_uint(r1) & 0xFFFF0000u;
    float r2 = r1 - __uint_as_float(mu);
    unsigned lu = __float_as_uint(r2) & 0xFFFF0000u;
    hs = (short)(hu >> 16); ms = (short)(mu >> 16); ls = (short)(lu >> 16);
}

#define MFMA6(acc, AH, AM, AL, BH, BM, BL) \
    acc = __builtin_amdgcn_mfma_f32_16x16x32_bf16(AL, BH, acc, 0, 0, 0); \
    acc = __builtin_amdgcn_mfma_f32_16x16x32_bf16(AM, BM, acc, 0, 0, 0); \
    acc = __builtin_amdgcn_mfma_f32_16x16x32_bf16(AH, BL, acc, 0, 0, 0); \
    acc = __builtin_amdgcn_mfma_f32_16x16x32_bf16(AM, BH, acc, 0, 0, 0); \
    acc = __builtin_amdgcn_mfma_f32_16x16x32_bf16(AH, BM, acc, 0, 0, 0); \
    acc = __builtin_amdgcn_mfma_f32_16x16x32_bf16(AH, BH, acc, 0, 0, 0);

// ---------------------------------------------------------------------------
// prep: split W per round into Wd (bf16x3) and Wc-Wd (bf16x3) planes.
// ---------------------------------------------------------------------------
__global__ void k_prep(const float* __restrict__ w_nb, short* __restrict__ wS)
{
    int i = blockIdx.x * 256 + threadIdx.x;     // 0 .. 2*64*64-1
    int r = i >> 12, oc = i & 4095;
    int o = oc >> 6, c = oc & 63;
    const float* wr = w_nb + (size_t)r * Hh * 2 * Hh + (size_t)o * 2 * Hh;
    float wc = wr[c], wd = wr[Hh + c];
    short* base = wS + (size_t)r * 6 * 4096;
    short h_, m_, l_;
    split3(wd, h_, m_, l_);
    base[0 * 4096 + oc] = h_; base[1 * 4096 + oc] = m_; base[2 * 4096 + oc] = l_;
    split3(wc - wd, h_, m_, l_);
    base[3 * 4096 + oc] = h_; base[4 * 4096 + oc] = m_; base[5 * 4096 + oc] = l_;
}

// ---------------------------------------------------------------------------
// t1 + t2 fused + split-plane output. Second layer vectorized float4
// (accumulation order c-ascending -> bit-identical to scalar version).
// ---------------------------------------------------------------------------
__global__ __launch_bounds__(256) void k_t12(
    const float* __restrict__ x,
    const float* __restrict__ w1, const float* __restrict__ g1, const float* __restrict__ b1,
    const float* __restrict__ w2, const float* __restrict__ g2, const float* __restrict__ b2,
    float* __restrict__ h, short* __restrict__ hS, float* __restrict__ sq)
{
    int t = threadIdx.x;
    int grp = t >> 6, o = t & 63;
    int p = blockIdx.x * 4 + grp;
    int b = p >> 9, n = p & 511;

    __shared__ float h1s[4][64];
    const float inv = rsqrtf(1.0f + EPSf);

    float acc = 0.0f;
#pragma unroll
    for (int c = 0; c < Cc; ++c)
        acc = fmaf(w1[o * Cc + c], x[(b * Cc + c) * Nn + n], acc);
    acc = fmaf(acc, g1[o] * inv, b1[o]);
    acc = fmaxf(acc, 0.0f);
    h1s[grp][o] = acc;
    __syncthreads();

    float a2 = 0.0f;
    {
        const float4* w2v = (const float4*)(w2 + (size_t)o * Hh);
        const float4* h1v = (const float4*)&h1s[grp][0];
#pragma unroll
        for (int c4 = 0; c4 < 16; ++c4) {
            float4 wv = w2v[c4], hv = h1v[c4];
            a2 = fmaf(wv.x, hv.x, a2);
            a2 = fmaf(wv.y, hv.y, a2);
            a2 = fmaf(wv.z, hv.z, a2);
            a2 = fmaf(wv.w, hv.w, a2);
        }
    }
    a2 = fmaf(a2, g2[o] * inv, b2[o]);
    a2 = fmaxf(a2, 0.0f);
    h[(size_t)p * Hh + o] = a2;
    short hs_, ms_, ls_;
    split3(a2, hs_, ms_, ls_);
    hS[0 * PLN + (size_t)p * Hh + o] = hs_;
    hS[1 * PLN + (size_t)p * Hh + o] = ms_;
    hS[2 * PLN + (size_t)p * Hh + o] = ls_;

    float s = a2 * a2;
#pragma unroll
    for (int off = 32; off > 0; off >>= 1) s += __shfl_down(s, off, 64);
    if (o == 0) sq[p] = s;
}

// ---------------------------------------------------------------------------
// kNN: Gram via MFMA (bf16x3 split). XCD-aware swizzle: all 32 blocks of a
// batch share blockIdx%8 so the batch's hS rows stay in ONE XCD's L2.
// Selection identical to round 8.
// ---------------------------------------------------------------------------
__global__ __launch_bounds__(256) void k_knn(
    const short* __restrict__ hS, const float* __restrict__ sq, int* __restrict__ idxout)
{
    int xcd = blockIdx.x & 7;
    int s_  = blockIdx.x >> 3;             // 0..511
    int b   = xcd + ((s_ >> 5) << 3);      // batch, b%8 == xcd
    int n0  = (s_ & 31) << 4;              // 16 centers
    int t   = threadIdx.x;

    __shared__ unsigned int keysLDS[16 * 512];   // 32 KB
    __shared__ float sqS[512];

    if (t < 128) ((float4*)sqS)[t] = ((const float4*)(sq + (size_t)b * Nn))[t];
    __syncthreads();

    int wv = t >> 6, lane = t & 63, col = lane & 15, quad = lane >> 4;
    const size_t rowbase = (size_t)b * Nn * Hh;

    bf16x8 AH[2], AM[2], AL[2];
    {
        const short* crow = hS + rowbase + (size_t)(n0 + col) * Hh;
#pragma unroll
        for (int ks = 0; ks < 2; ++ks) {
            int aoff = ks * 32 + quad * 8;
            AH[ks] = *(const bf16x8*)(crow + 0 * PLN + aoff);
            AM[ks] = *(const bf16x8*)(crow + 1 * PLN + aoff);
            AL[ks] = *(const bf16x8*)(crow + 2 * PLN + aoff);
        }
    }
    float sqcr[4];
#pragma unroll
    for (int r_ = 0; r_ < 4; ++r_) sqcr[r_] = sqS[n0 + quad * 4 + r_];

    for (int i = 0; i < 8; ++i) {
        int nt = wv * 8 + i;
        const short* prow = hS + rowbase + (size_t)(nt * 16 + col) * Hh;
        f32x4 acc = (f32x4){0.f, 0.f, 0.f, 0.f};
#pragma unroll
        for (int ks = 0; ks < 2; ++ks) {
            int aoff = ks * 32 + quad * 8;
            bf16x8 BH = *(const bf16x8*)(prow + 0 * PLN + aoff);
            bf16x8 BM = *(const bf16x8*)(prow + 1 * PLN + aoff);
            bf16x8 BL = *(const bf16x8*)(prow + 2 * PLN + aoff);
            MFMA6(acc, AH[ks], AM[ks], AL[ks], BH, BM, BL)
        }
        float sqp = sqS[nt * 16 + col];
#pragma unroll
        for (int r_ = 0; r_ < 4; ++r_) {
            int ctr = quad * 4 + r_;
            float d = sqcr[r_] + sqp - 2.0f * acc[r_];
            unsigned int u = __float_as_uint(d);
            u = ((int)u < 0) ? ~u : (u | 0x80000000u);
            keysLDS[ctr * 512 + nt * 16 + col] = u;
        }
    }
    __syncthreads();

    unsigned int kk[4][8];
    int rr[4][8];
#pragma unroll
    for (int s = 0; s < 4; ++s) {
        int jj = wv * 4 + s;
        const uint4* kp = (const uint4*)&keysLDS[jj * 512 + (lane << 3)];
        uint4 A = kp[0], Bq = kp[1];
        kk[s][0] = A.x;  kk[s][1] = A.y;  kk[s][2] = A.z;  kk[s][3] = A.w;
        kk[s][4] = Bq.x; kk[s][5] = Bq.y; kk[s][6] = Bq.z; kk[s][7] = Bq.w;
#pragma unroll
        for (int q = 0; q < 8; ++q) rr[s][q] = q;
    }

#define CE(s, i, j_) { \
    bool sw = (kk[s][i] > kk[s][j_]) || (kk[s][i] == kk[s][j_] && rr[s][i] > rr[s][j_]); \
    unsigned int tk = sw ? kk[s][i] : kk[s][j_]; kk[s][i] = sw ? kk[s][j_] : kk[s][i]; kk[s][j_] = tk; \
    int tr = sw ? rr[s][i] : rr[s][j_]; rr[s][i] = sw ? rr[s][j_] : rr[s][i]; rr[s][j_] = tr; }
#pragma unroll
    for (int s = 0; s < 4; ++s) {
        CE(s,0,1) CE(s,2,3) CE(s,4,5) CE(s,6,7)
        CE(s,0,2) CE(s,1,3) CE(s,4,6) CE(s,5,7)
        CE(s,1,2) CE(s,5,6)
        CE(s,0,4) CE(s,1,5) CE(s,2,6) CE(s,3,7)
        CE(s,2,4) CE(s,3,5)
        CE(s,1,2) CE(s,3,4) CE(s,5,6)
    }
#undef CE

    int outbase[4];
#pragma unroll
    for (int s = 0; s < 4; ++s) outbase[s] = (b * Nn + n0 + wv * 4 + s) * Kk;

    for (int iter = 0; iter < Kk; ++iter) {
        unsigned int mv[4];
#pragma unroll
        for (int s = 0; s < 4; ++s) mv[s] = kk[s][0];
#define DSTEP(ctrl) { \
        _Pragma("unroll") \
        for (int s = 0; s < 4; ++s) { \
            unsigned int ov = (unsigned int)__builtin_amdgcn_update_dpp((int)mv[s], (int)mv[s], ctrl, 0xF, 0xF, false); \
            mv[s] = (ov < mv[s]) ? ov : mv[s]; } }
        DSTEP(0xB1)   // quad_perm xor1
        DSTEP(0x4E)   // quad_perm xor2
        DSTEP(0x124)  // row_ror:4
        DSTEP(0x128)  // row_ror:8
#undef DSTEP
#pragma unroll
        for (int s = 0; s < 4; ++s) {
            unsigned int ov = (unsigned int)__builtin_amdgcn_ds_swizzle((int)mv[s], 0x401F);
            mv[s] = (ov < mv[s]) ? ov : mv[s];
        }
#pragma unroll
        for (int s = 0; s < 4; ++s) {
            unsigned int ov = __shfl_xor(mv[s], 32, 64);
            mv[s] = (ov < mv[s]) ? ov : mv[s];
        }
#pragma unroll
        for (int s = 0; s < 4; ++s) {
            unsigned long long bal = __ballot(kk[s][0] == mv[s]);
            int wn = __ffsll(bal) - 1;
            if (lane == wn) {
                idxout[outbase[s] + iter] = (lane << 3) + rr[s][0];
#pragma unroll
                for (int q = 0; q < 7; ++q) { kk[s][q] = kk[s][q + 1]; rr[s][q] = rr[s][q + 1]; }
                kk[s][7] = 0xFFFFFFFFu;
            }
        }
    }
}

// ---------------------------------------------------------------------------
// EdgeConv via MFMA, base/delta decomposition + XCD-aware swizzle
// (same-batch blocks share an XCD -> neighbor gathers hit local L2).
// ---------------------------------------------------------------------------
__global__ __launch_bounds__(256, 4) void k_edge(
    const float* __restrict__ h, const short* __restrict__ hS,
    const int* __restrict__ idx,
    const short* __restrict__ wS,
    const float* __restrict__ g, const float* __restrict__ bb_,
    float* __restrict__ hout, short* __restrict__ hSout, float* __restrict__ sqout)
{
    __shared__ short wLDS[3][64 * 72];
    __shared__ float baseS[16 * 68];
    __shared__ int   idxS[256];

    int t   = threadIdx.x;
    int xcd = blockIdx.x & 7;
    int s_  = blockIdx.x >> 3;
    int b   = xcd + ((s_ >> 5) << 3);
    int p0  = b * Nn + ((s_ & 31) << 4);

    idxS[t] = idx[p0 * Kk + t];
#pragma unroll
    for (int it = 0; it < 6; ++it) {
        int f = it * 256 + t;
        int plane = f >> 9;
        int i8 = f & 511;
        int o = i8 >> 3, c8 = i8 & 7;
        uint4 v = ((const uint4*)(wS + (size_t)(3 + plane) * 4096))[i8];
        *(uint4*)&wLDS[plane][o * 72 + c8 * 8] = v;
    }
    __syncthreads();

    int wv = t >> 6, lane = t & 63, col = lane & 15, quad = lane >> 4;

    {
        f32x4 bacc = (f32x4){0.f, 0.f, 0.f, 0.f};
        const short* hrow = hS + (size_t)(p0 + col) * Hh;
#pragma unroll
        for (int ks = 0; ks < 2; ++ks) {
            int aoff = ks * 32 + quad * 8;
            bf16x8 AH = *(const bf16x8*)(hrow + 0 * PLN + aoff);
            bf16x8 AM = *(const bf16x8*)(hrow + 1 * PLN + aoff);
            bf16x8 AL = *(const bf16x8*)(hrow + 2 * PLN + aoff);
            int boff = (wv * 16 + col) * 72 + aoff;
            bf16x8 BH = *(bf16x8*)&wLDS[0][boff];
            bf16x8 BM = *(bf16x8*)&wLDS[1][boff];
            bf16x8 BL = *(bf16x8*)&wLDS[2][boff];
            MFMA6(bacc, AH, AM, AL, BH, BM, BL)
        }
#pragma unroll
        for (int r_ = 0; r_ < 4; ++r_)
            baseS[(quad * 4 + r_) * 68 + wv * 16 + col] = bacc[r_];
    }
    __syncthreads();

#pragma unroll
    for (int it = 0; it < 6; ++it) {
        int f = it * 256 + t;
        int plane = f >> 9;
        int i8 = f & 511;
        int o = i8 >> 3, c8 = i8 & 7;
        uint4 v = ((const uint4*)(wS + (size_t)plane * 4096))[i8];
        *(uint4*)&wLDS[plane][o * 72 + c8 * 8] = v;
    }
    __syncthreads();

    const float inv = rsqrtf(1.0f + EPSf);
    float scv[4], bov[4];
#pragma unroll
    for (int nt = 0; nt < 4; ++nt) {
        scv[nt] = g[nt * 16 + col] * inv;
        bov[nt] = bb_[nt * 16 + col];
    }

    for (int pr = 0; pr < 2; ++pr) {
        bf16x8 A[2][2][3];
#pragma unroll
        for (int pt2 = 0; pt2 < 2; ++pt2) {
            int pl = wv * 4 + pr * 2 + pt2;
            int j = idxS[pl * 16 + col];
            const short* nrow = hS + ((size_t)(b * Nn) + j) * Hh;
#pragma unroll
            for (int ks = 0; ks < 2; ++ks) {
                int aoff = ks * 32 + quad * 8;
                A[pt2][ks][0] = *(const bf16x8*)(nrow + 0 * PLN + aoff);
                A[pt2][ks][1] = *(const bf16x8*)(nrow + 1 * PLN + aoff);
                A[pt2][ks][2] = *(const bf16x8*)(nrow + 2 * PLN + aoff);
            }
        }

        f32x4 acc[2][4];
#pragma unroll
        for (int pt2 = 0; pt2 < 2; ++pt2)
#pragma unroll
            for (int nt = 0; nt < 4; ++nt)
                acc[pt2][nt] = (f32x4){0.f, 0.f, 0.f, 0.f};

#pragma unroll
        for (int ks = 0; ks < 2; ++ks)
#pragma unroll
            for (int nt = 0; nt < 4; ++nt) {
                int boff = (nt * 16 + col) * 72 + ks * 32 + quad * 8;
                bf16x8 BH = *(bf16x8*)&wLDS[0][boff];
                bf16x8 BM = *(bf16x8*)&wLDS[1][boff];
                bf16x8 BL = *(bf16x8*)&wLDS[2][boff];
#pragma unroll
                for (int pt2 = 0; pt2 < 2; ++pt2) {
                    f32x4 a = acc[pt2][nt];
                    MFMA6(a, A[pt2][ks][0], A[pt2][ks][1], A[pt2][ks][2], BH, BM, BL)
                    acc[pt2][nt] = a;
                }
            }

#pragma unroll
        for (int pt2 = 0; pt2 < 2; ++pt2) {
            int pl = wv * 4 + pr * 2 + pt2;
            int pglob = p0 + pl;
            float res[4];
#pragma unroll
            for (int nt = 0; nt < 4; ++nt) {
                float base = baseS[pl * 68 + nt * 16 + col];
                f32x4 a = acc[pt2][nt];
                float v0 = fmaf(base + a[0], scv[nt], bov[nt]);
                float v1 = fmaf(base + a[1], scv[nt], bov[nt]);
                float v2 = fmaf(base + a[2], scv[nt], bov[nt]);
                float v3 = fmaf(base + a[3], scv[nt], bov[nt]);
                float vm = fmaxf(fmaxf(v0, v1), fmaxf(v2, v3));
                vm = fmaxf(vm, __shfl_xor(vm, 16));
                vm = fmaxf(vm, __shfl_xor(vm, 32));
                res[nt] = fmaxf(vm, 0.0f);
            }
            float rv = res[quad];
            hout[(size_t)pglob * Hh + lane] = rv;
            short hs_, ms_, ls_;
            split3(rv, hs_, ms_, ls_);
            hSout[0 * PLN + (size_t)pglob * Hh + lane] = hs_;
            hSout[1 * PLN + (size_t)pglob * Hh + lane] = ms_;
            hSout[2 * PLN + (size_t)pglob * Hh + lane] = ls_;

            float s = res[0] * res[0] + res[1] * res[1]
                    + res[2] * res[2] + res[3] * res[3];
            s += __shfl_xor(s, 1);
            s += __shfl_xor(s, 2);
            s += __shfl_xor(s, 4);
            s += __shfl_xor(s, 8);
            if (lane == 0) sqout[pglob] = s;
        }
    }
}

// ---------------------------------------------------------------------------
// head: vectorized float4 (accumulation order c-ascending, bit-identical)
// ---------------------------------------------------------------------------
__global__ __launch_bounds__(256) void k_head(
    const float* __restrict__ h,
    const float* __restrict__ w1, const float* __restrict__ g1, const float* __restrict__ b1,
    const float* __restrict__ w2, const float* __restrict__ b2,
    float* __restrict__ out)
{
    __shared__ float hcS[4][64];
    int t = threadIdx.x;
    int grp = t >> 6, o = t & 63;
    int p = blockIdx.x * 4 + grp;

    hcS[grp][o] = h[(size_t)p * Hh + o];
    __syncthreads();

    const float inv = rsqrtf(1.0f + EPSf);
    float acc = 0.0f;
    {
        const float4* w1v = (const float4*)(w1 + (size_t)o * Hh);
        const float4* hv4 = (const float4*)&hcS[grp][0];
#pragma unroll
        for (int c4 = 0; c4 < 16; ++c4) {
            float4 wv = w1v[c4], hv = hv4[c4];
            acc = fmaf(wv.x, hv.x, acc);
            acc = fmaf(wv.y, hv.y, acc);
            acc = fmaf(wv.z, hv.z, acc);
            acc = fmaf(wv.w, hv.w, acc);
        }
    }
    acc = fmaxf(fmaf(acc, g1[o] * inv, b1[o]), 0.0f);

    float v = acc * w2[o];
#pragma unroll
    for (int off = 32; off > 0; off >>= 1) v += __shfl_down(v, off, 64);
    if (o == 0) out[p] = v + b2[0];
}

// ---------------------------------------------------------------------------
extern "C" void kernel_launch(void* const* d_in, const int* in_sizes, int n_in,
                              void* d_out, int out_size, void* d_ws, size_t ws_size,
                              hipStream_t stream)
{
    const float* x    = (const float*)d_in[0];
    const float* w_t1 = (const float*)d_in[1];
    const float* g_t1 = (const float*)d_in[2];
    const float* b_t1 = (const float*)d_in[3];
    const float* w_t2 = (const float*)d_in[4];
    const float* g_t2 = (const float*)d_in[5];
    const float* b_t2 = (const float*)d_in[6];
    const float* w_nb = (const float*)d_in[7];
    const float* g_nb = (const float*)d_in[8];
    const float* b_nb = (const float*)d_in[9];
    const float* w_s1 = (const float*)d_in[10];
    const float* g_s1 = (const float*)d_in[11];
    const float* b_s1 = (const float*)d_in[12];
    const float* w_s2 = (const float*)d_in[13];
    const float* b_s2 = (const float*)d_in[14];
    float* out = (float*)d_out;

    float* hA  = (float*)d_ws;
    float* hB  = hA + PLN;
    float* sq  = hB + PLN;
    int*   idx = (int*)(sq + (size_t)Bn * Nn);
    short* hSa = (short*)(idx + (size_t)Bn * Nn * Kk);
    short* hSb = hSa + 3 * PLN;
    short* wS  = hSb + 3 * PLN;

    k_prep<<<32, 256, 0, stream>>>(w_nb, wS);
    k_t12<<<Bn * Nn / 4, 256, 0, stream>>>(x, w_t1, g_t1, b_t1, w_t2, g_t2, b_t2,
                                           hA, hSa, sq);

    const float* hin = hA;
    float* hout = hB;
    const short* hSin = hSa;
    short* hSout = hSb;
    for (int r = 0; r < Rr; ++r) {
        k_knn<<<Bn * (Nn / 16), 256, 0, stream>>>(hSin, sq, idx);
        k_edge<<<Bn * Nn / 16, 256, 0, stream>>>(hin, hSin, idx,
            wS + (size_t)r * 6 * 4096, g_nb + r * Hh, b_nb + r * Hh,
            hout, hSout, sq);
        const float* tf = hout; hout = (float*)hin; hin = tf;
        const short* ts = hSout; hSout = (short*)hSin; hSin = ts;
    }
    k_head<<<Bn * Nn / 4, 256, 0, stream>>>(hin, w_s1, g_s1, b_s1, w_s2, b_s2, out);
}

// Round 10
// 478.730 us; speedup vs baseline: 1.9055x; 1.4427x over previous
//
#include <hip/hip_runtime.h>
#include <math.h>

#define Bn 128
#define Nn 512
#define Cc 7
#define Hh 64
#define Kk 16
#define Rr 2
#define EPSf 1e-5f

typedef __attribute__((ext_vector_type(8))) short bf16x8;
typedef __attribute__((ext_vector_type(4))) float f32x4;

#define PLN ((size_t)4194304)   // elements per h-split plane (B*N*H)

// exact truncation split: a = hi + mid + lo + r, |r| <= 2^-24 |a|
__device__ __forceinline__ void split3(float a, short &hs, short &ms, short &ls) {
    unsigned u  = __float_as_uint(a);
    unsigned hu = u & 0xFFFF0000u;
    float r1 = a - __uint_as_float(hu);
    unsigned mu = __float_as_uint(r1) & 0xFFFF0000u;
    float r2 = r1 - __uint_as_float(mu);
    unsigned lu = __float_as_uint(r2) & 0xFFFF0000u;
    hs = (short)(hu >> 16); ms = (short)(mu >> 16); ls = (short)(lu >> 16);
}

#define MFMA6(acc, AH, AM, AL, BH, BM, BL) \
    acc = __builtin_amdgcn_mfma_f32_16x16x32_bf16(AL, BH, acc, 0, 0, 0); \
    acc = __builtin_amdgcn_mfma_f32_16x16x32_bf16(AM, BM, acc, 0, 0, 0); \
    acc = __builtin_amdgcn_mfma_f32_16x16x32_bf16(AH, BL, acc, 0, 0, 0); \
    acc = __builtin_amdgcn_mfma_f32_16x16x32_bf16(AM, BH, acc, 0, 0, 0); \
    acc = __builtin_amdgcn_mfma_f32_16x16x32_bf16(AH, BM, acc, 0, 0, 0); \
    acc = __builtin_amdgcn_mfma_f32_16x16x32_bf16(AH, BH, acc, 0, 0, 0);

// ---------------------------------------------------------------------------
// prep: split weights into bf16x3 planes.
// wS layout (4096-short planes): [r0: wd x3, wcd x3][r1: wd x3, wcd x3]
//                                [w_t2 x3][w_s1 x3]   (18 planes total)
// ---------------------------------------------------------------------------
__global__ void k_prep(const float* __restrict__ w_nb, const float* __restrict__ w_t2,
                       const float* __restrict__ w_s1, short* __restrict__ wS)
{
    int i = blockIdx.x * 256 + threadIdx.x;     // 0 .. 16383
    short h_, m_, l_;
    if (i < 8192) {
        int r = i >> 12, oc = i & 4095;
        int o = oc >> 6, c = oc & 63;
        const float* wr = w_nb + (size_t)r * Hh * 2 * Hh + (size_t)o * 2 * Hh;
        float wc = wr[c], wd = wr[Hh + c];
        short* base = wS + (size_t)r * 6 * 4096;
        split3(wd, h_, m_, l_);
        base[0 * 4096 + oc] = h_; base[1 * 4096 + oc] = m_; base[2 * 4096 + oc] = l_;
        split3(wc - wd, h_, m_, l_);
        base[3 * 4096 + oc] = h_; base[4 * 4096 + oc] = m_; base[5 * 4096 + oc] = l_;
    } else {
        int which = (i - 8192) >> 12;            // 0: w_t2, 1: w_s1
        int oc = i & 4095;
        const float* src = which ? w_s1 : w_t2;
        short* base = wS + (size_t)(12 + which * 3) * 4096;
        split3(src[oc], h_, m_, l_);
        base[0 * 4096 + oc] = h_; base[1 * 4096 + oc] = m_; base[2 * 4096 + oc] = l_;
    }
}

// ---------------------------------------------------------------------------
// t1 + t2: layer 1 fp32 VALU (bit-exact), layer 2 via MFMA6 from split planes.
// Block = 16 points. Emits hS split planes + sq. No fp32 h output.
// ---------------------------------------------------------------------------
__global__ __launch_bounds__(256) void k_t12(
    const float* __restrict__ x,
    const float* __restrict__ w1, const float* __restrict__ g1, const float* __restrict__ b1,
    const short* __restrict__ wS2, const float* __restrict__ g2, const float* __restrict__ b2,
    short* __restrict__ hS, float* __restrict__ sq)
{
    __shared__ short wLDS[3][64 * 80];
    __shared__ short h1S[3][16 * 80];
    __shared__ float sqP[16][4];

    int t  = threadIdx.x;
    int p0 = blockIdx.x * 16;
    int b  = p0 >> 9, n0 = p0 & 511;

    // stage W2 splits (coalesced)
#pragma unroll
    for (int it = 0; it < 6; ++it) {
        int f = it * 256 + t;              // uint4 index 0..1535
        int plane = f >> 9, i8 = f & 511;
        int o = i8 >> 3, c8 = i8 & 7;
        uint4 v = ((const uint4*)(wS2 + (size_t)plane * 4096))[i8];
        *(uint4*)&wLDS[plane][o * 80 + c8 * 8] = v;
    }

    // layer 1 (bit-exact fp32) + split into LDS
    {
        int pt = t & 15, ow = t >> 4;
        const float inv = rsqrtf(1.0f + EPSf);
        float xv[Cc];
#pragma unroll
        for (int c = 0; c < Cc; ++c)
            xv[c] = x[(b * Cc + c) * Nn + n0 + pt];
#pragma unroll
        for (int j = 0; j < 4; ++j) {
            int o = ow + 16 * j;
            float acc = 0.0f;
#pragma unroll
            for (int c = 0; c < Cc; ++c)
                acc = fmaf(w1[o * Cc + c], xv[c], acc);
            acc = fmaf(acc, g1[o] * inv, b1[o]);
            acc = fmaxf(acc, 0.0f);
            short hs_, ms_, ls_;
            split3(acc, hs_, ms_, ls_);
            h1S[0][pt * 80 + o] = hs_;
            h1S[1][pt * 80 + o] = ms_;
            h1S[2][pt * 80 + o] = ls_;
        }
    }
    __syncthreads();

    int wv = t >> 6, lane = t & 63, col = lane & 15, quad = lane >> 4;
    const float inv = rsqrtf(1.0f + EPSf);

    // MFMA: A = h1 points (m=col), B = W2 rows o (n=col), D[pt][o]
    f32x4 acc = (f32x4){0.f, 0.f, 0.f, 0.f};
#pragma unroll
    for (int ks = 0; ks < 2; ++ks) {
        int aoff = ks * 32 + quad * 8;
        bf16x8 AH = *(bf16x8*)&h1S[0][col * 80 + aoff];
        bf16x8 AM = *(bf16x8*)&h1S[1][col * 80 + aoff];
        bf16x8 AL = *(bf16x8*)&h1S[2][col * 80 + aoff];
        int boff = (wv * 16 + col) * 80 + aoff;
        bf16x8 BH = *(bf16x8*)&wLDS[0][boff];
        bf16x8 BM = *(bf16x8*)&wLDS[1][boff];
        bf16x8 BL = *(bf16x8*)&wLDS[2][boff];
        MFMA6(acc, AH, AM, AL, BH, BM, BL)
    }

    int o = wv * 16 + col;
    float sc = g2[o] * inv, bo = b2[o];
    float s4[4];
#pragma unroll
    for (int r = 0; r < 4; ++r) {
        int pt = quad * 4 + r;
        float a2 = fmaf(acc[r], sc, bo);
        a2 = fmaxf(a2, 0.0f);
        short hs_, ms_, ls_;
        split3(a2, hs_, ms_, ls_);
        size_t rowp = (size_t)(p0 + pt) * Hh + o;
        hS[0 * PLN + rowp] = hs_;
        hS[1 * PLN + rowp] = ms_;
        hS[2 * PLN + rowp] = ls_;
        s4[r] = a2 * a2;
    }
#pragma unroll
    for (int sh = 1; sh < 16; sh <<= 1) {
#pragma unroll
        for (int r = 0; r < 4; ++r) s4[r] += __shfl_xor(s4[r], sh, 64);
    }
    if (col == 0) {
#pragma unroll
        for (int r = 0; r < 4; ++r) sqP[quad * 4 + r][wv] = s4[r];
    }
    __syncthreads();
    if (t < 16) sq[p0 + t] = sqP[t][0] + sqP[t][1] + sqP[t][2] + sqP[t][3];
}

// ---------------------------------------------------------------------------
// kNN: Gram via MFMA + XCD swizzle + 4-chain DPP selection (unchanged R9)
// ---------------------------------------------------------------------------
__global__ __launch_bounds__(256) void k_knn(
    const short* __restrict__ hS, const float* __restrict__ sq, int* __restrict__ idxout)
{
    int xcd = blockIdx.x & 7;
    int s_  = blockIdx.x >> 3;
    int b   = xcd + ((s_ >> 5) << 3);
    int n0  = (s_ & 31) << 4;
    int t   = threadIdx.x;

    __shared__ unsigned int keysLDS[16 * 512];
    __shared__ float sqS[512];

    if (t < 128) ((float4*)sqS)[t] = ((const float4*)(sq + (size_t)b * Nn))[t];
    __syncthreads();

    int wv = t >> 6, lane = t & 63, col = lane & 15, quad = lane >> 4;
    const size_t rowbase = (size_t)b * Nn * Hh;

    bf16x8 AH[2], AM[2], AL[2];
    {
        const short* crow = hS + rowbase + (size_t)(n0 + col) * Hh;
#pragma unroll
        for (int ks = 0; ks < 2; ++ks) {
            int aoff = ks * 32 + quad * 8;
            AH[ks] = *(const bf16x8*)(crow + 0 * PLN + aoff);
            AM[ks] = *(const bf16x8*)(crow + 1 * PLN + aoff);
            AL[ks] = *(const bf16x8*)(crow + 2 * PLN + aoff);
        }
    }
    float sqcr[4];
#pragma unroll
    for (int r_ = 0; r_ < 4; ++r_) sqcr[r_] = sqS[n0 + quad * 4 + r_];

    for (int i = 0; i < 8; ++i) {
        int nt = wv * 8 + i;
        const short* prow = hS + rowbase + (size_t)(nt * 16 + col) * Hh;
        f32x4 acc = (f32x4){0.f, 0.f, 0.f, 0.f};
#pragma unroll
        for (int ks = 0; ks < 2; ++ks) {
            int aoff = ks * 32 + quad * 8;
            bf16x8 BH = *(const bf16x8*)(prow + 0 * PLN + aoff);
            bf16x8 BM = *(const bf16x8*)(prow + 1 * PLN + aoff);
            bf16x8 BL = *(const bf16x8*)(prow + 2 * PLN + aoff);
            MFMA6(acc, AH[ks], AM[ks], AL[ks], BH, BM, BL)
        }
        float sqp = sqS[nt * 16 + col];
#pragma unroll
        for (int r_ = 0; r_ < 4; ++r_) {
            int ctr = quad * 4 + r_;
            float d = sqcr[r_] + sqp - 2.0f * acc[r_];
            unsigned int u = __float_as_uint(d);
            u = ((int)u < 0) ? ~u : (u | 0x80000000u);
            keysLDS[ctr * 512 + nt * 16 + col] = u;
        }
    }
    __syncthreads();

    unsigned int kk[4][8];
    int rr[4][8];
#pragma unroll
    for (int s = 0; s < 4; ++s) {
        int jj = wv * 4 + s;
        const uint4* kp = (const uint4*)&keysLDS[jj * 512 + (lane << 3)];
        uint4 A = kp[0], Bq = kp[1];
        kk[s][0] = A.x;  kk[s][1] = A.y;  kk[s][2] = A.z;  kk[s][3] = A.w;
        kk[s][4] = Bq.x; kk[s][5] = Bq.y; kk[s][6] = Bq.z; kk[s][7] = Bq.w;
#pragma unroll
        for (int q = 0; q < 8; ++q) rr[s][q] = q;
    }

#define CE(s, i, j_) { \
    bool sw = (kk[s][i] > kk[s][j_]) || (kk[s][i] == kk[s][j_] && rr[s][i] > rr[s][j_]); \
    unsigned int tk = sw ? kk[s][i] : kk[s][j_]; kk[s][i] = sw ? kk[s][j_] : kk[s][i]; kk[s][j_] = tk; \
    int tr = sw ? rr[s][i] : rr[s][j_]; rr[s][i] = sw ? rr[s][j_] : rr[s][i]; rr[s][j_] = tr; }
#pragma unroll
    for (int s = 0; s < 4; ++s) {
        CE(s,0,1) CE(s,2,3) CE(s,4,5) CE(s,6,7)
        CE(s,0,2) CE(s,1,3) CE(s,4,6) CE(s,5,7)
        CE(s,1,2) CE(s,5,6)
        CE(s,0,4) CE(s,1,5) CE(s,2,6) CE(s,3,7)
        CE(s,2,4) CE(s,3,5)
        CE(s,1,2) CE(s,3,4) CE(s,5,6)
    }
#undef CE

    int outbase[4];
#pragma unroll
    for (int s = 0; s < 4; ++s) outbase[s] = (b * Nn + n0 + wv * 4 + s) * Kk;

    for (int iter = 0; iter < Kk; ++iter) {
        unsigned int mv[4];
#pragma unroll
        for (int s = 0; s < 4; ++s) mv[s] = kk[s][0];
#define DSTEP(ctrl) { \
        _Pragma("unroll") \
        for (int s = 0; s < 4; ++s) { \
            unsigned int ov = (unsigned int)__builtin_amdgcn_update_dpp((int)mv[s], (int)mv[s], ctrl, 0xF, 0xF, false); \
            mv[s] = (ov < mv[s]) ? ov : mv[s]; } }
        DSTEP(0xB1)
        DSTEP(0x4E)
        DSTEP(0x124)
        DSTEP(0x128)
#undef DSTEP
#pragma unroll
        for (int s = 0; s < 4; ++s) {
            unsigned int ov = (unsigned int)__builtin_amdgcn_ds_swizzle((int)mv[s], 0x401F);
            mv[s] = (ov < mv[s]) ? ov : mv[s];
        }
#pragma unroll
        for (int s = 0; s < 4; ++s) {
            unsigned int ov = __shfl_xor(mv[s], 32, 64);
            mv[s] = (ov < mv[s]) ? ov : mv[s];
        }
#pragma unroll
        for (int s = 0; s < 4; ++s) {
            unsigned long long bal = __ballot(kk[s][0] == mv[s]);
            int wn = __ffsll(bal) - 1;
            if (lane == wn) {
                idxout[outbase[s] + iter] = (lane << 3) + rr[s][0];
#pragma unroll
                for (int q = 0; q < 7; ++q) { kk[s][q] = kk[s][q + 1]; rr[s][q] = rr[s][q + 1]; }
                kk[s][7] = 0xFFFFFFFFu;
            }
        }
    }
}

// ---------------------------------------------------------------------------
// EdgeConv via MFMA, base/delta, XCD swizzle. No fp32 h output (splits only).
// ---------------------------------------------------------------------------
__global__ __launch_bounds__(256, 4) void k_edge(
    const short* __restrict__ hS,
    const int* __restrict__ idx,
    const short* __restrict__ wS,
    const float* __restrict__ g, const float* __restrict__ bb_,
    short* __restrict__ hSout, float* __restrict__ sqout)
{
    __shared__ short wLDS[3][64 * 72];
    __shared__ float baseS[16 * 68];
    __shared__ int   idxS[256];

    int t   = threadIdx.x;
    int xcd = blockIdx.x & 7;
    int s_  = blockIdx.x >> 3;
    int b   = xcd + ((s_ >> 5) << 3);
    int p0  = b * Nn + ((s_ & 31) << 4);

    idxS[t] = idx[p0 * Kk + t];
#pragma unroll
    for (int it = 0; it < 6; ++it) {
        int f = it * 256 + t;
        int plane = f >> 9;
        int i8 = f & 511;
        int o = i8 >> 3, c8 = i8 & 7;
        uint4 v = ((const uint4*)(wS + (size_t)(3 + plane) * 4096))[i8];
        *(uint4*)&wLDS[plane][o * 72 + c8 * 8] = v;
    }
    __syncthreads();

    int wv = t >> 6, lane = t & 63, col = lane & 15, quad = lane >> 4;

    {
        f32x4 bacc = (f32x4){0.f, 0.f, 0.f, 0.f};
        const short* hrow = hS + (size_t)(p0 + col) * Hh;
#pragma unroll
        for (int ks = 0; ks < 2; ++ks) {
            int aoff = ks * 32 + quad * 8;
            bf16x8 AH = *(const bf16x8*)(hrow + 0 * PLN + aoff);
            bf16x8 AM = *(const bf16x8*)(hrow + 1 * PLN + aoff);
            bf16x8 AL = *(const bf16x8*)(hrow + 2 * PLN + aoff);
            int boff = (wv * 16 + col) * 72 + aoff;
            bf16x8 BH = *(bf16x8*)&wLDS[0][boff];
            bf16x8 BM = *(bf16x8*)&wLDS[1][boff];
            bf16x8 BL = *(bf16x8*)&wLDS[2][boff];
            MFMA6(bacc, AH, AM, AL, BH, BM, BL)
        }
#pragma unroll
        for (int r_ = 0; r_ < 4; ++r_)
            baseS[(quad * 4 + r_) * 68 + wv * 16 + col] = bacc[r_];
    }
    __syncthreads();

#pragma unroll
    for (int it = 0; it < 6; ++it) {
        int f = it * 256 + t;
        int plane = f >> 9;
        int i8 = f & 511;
        int o = i8 >> 3, c8 = i8 & 7;
        uint4 v = ((const uint4*)(wS + (size_t)plane * 4096))[i8];
        *(uint4*)&wLDS[plane][o * 72 + c8 * 8] = v;
    }
    __syncthreads();

    const float inv = rsqrtf(1.0f + EPSf);
    float scv[4], bov[4];
#pragma unroll
    for (int nt = 0; nt < 4; ++nt) {
        scv[nt] = g[nt * 16 + col] * inv;
        bov[nt] = bb_[nt * 16 + col];
    }

    for (int pr = 0; pr < 2; ++pr) {
        bf16x8 A[2][2][3];
#pragma unroll
        for (int pt2 = 0; pt2 < 2; ++pt2) {
            int pl = wv * 4 + pr * 2 + pt2;
            int j = idxS[pl * 16 + col];
            const short* nrow = hS + ((size_t)(b * Nn) + j) * Hh;
#pragma unroll
            for (int ks = 0; ks < 2; ++ks) {
                int aoff = ks * 32 + quad * 8;
                A[pt2][ks][0] = *(const bf16x8*)(nrow + 0 * PLN + aoff);
                A[pt2][ks][1] = *(const bf16x8*)(nrow + 1 * PLN + aoff);
                A[pt2][ks][2] = *(const bf16x8*)(nrow + 2 * PLN + aoff);
            }
        }

        f32x4 acc[2][4];
#pragma unroll
        for (int pt2 = 0; pt2 < 2; ++pt2)
#pragma unroll
            for (int nt = 0; nt < 4; ++nt)
                acc[pt2][nt] = (f32x4){0.f, 0.f, 0.f, 0.f};

#pragma unroll
        for (int ks = 0; ks < 2; ++ks)
#pragma unroll
            for (int nt = 0; nt < 4; ++nt) {
                int boff = (nt * 16 + col) * 72 + ks * 32 + quad * 8;
                bf16x8 BH = *(bf16x8*)&wLDS[0][boff];
                bf16x8 BM = *(bf16x8*)&wLDS[1][boff];
                bf16x8 BL = *(bf16x8*)&wLDS[2][boff];
#pragma unroll
                for (int pt2 = 0; pt2 < 2; ++pt2) {
                    f32x4 a = acc[pt2][nt];
                    MFMA6(a, A[pt2][ks][0], A[pt2][ks][1], A[pt2][ks][2], BH, BM, BL)
                    acc[pt2][nt] = a;
                }
            }

#pragma unroll
        for (int pt2 = 0; pt2 < 2; ++pt2) {
            int pl = wv * 4 + pr * 2 + pt2;
            int pglob = p0 + pl;
            float res[4];
#pragma unroll
            for (int nt = 0; nt < 4; ++nt) {
                float base = baseS[pl * 68 + nt * 16 + col];
                f32x4 a = acc[pt2][nt];
                float v0 = fmaf(base + a[0], scv[nt], bov[nt]);
                float v1 = fmaf(base + a[1], scv[nt], bov[nt]);
                float v2 = fmaf(base + a[2], scv[nt], bov[nt]);
                float v3 = fmaf(base + a[3], scv[nt], bov[nt]);
                float vm = fmaxf(fmaxf(v0, v1), fmaxf(v2, v3));
                vm = fmaxf(vm, __shfl_xor(vm, 16));
                vm = fmaxf(vm, __shfl_xor(vm, 32));
                res[nt] = fmaxf(vm, 0.0f);
            }
            float rv = res[quad];
            short hs_, ms_, ls_;
            split3(rv, hs_, ms_, ls_);
            hSout[0 * PLN + (size_t)pglob * Hh + lane] = hs_;
            hSout[1 * PLN + (size_t)pglob * Hh + lane] = ms_;
            hSout[2 * PLN + (size_t)pglob * Hh + lane] = ls_;

            float s = res[0] * res[0] + res[1] * res[1]
                    + res[2] * res[2] + res[3] * res[3];
            s += __shfl_xor(s, 1);
            s += __shfl_xor(s, 2);
            s += __shfl_xor(s, 4);
            s += __shfl_xor(s, 8);
            if (lane == 0) sqout[pglob] = s;
        }
    }
}

// ---------------------------------------------------------------------------
// head via MFMA: A = final h splits (global), B = w_s1 splits (LDS).
// logits = sum_o relu(bn(s1)) * w_s2[o] + b_s2 via cross-lane + LDS reduce.
// ---------------------------------------------------------------------------
__global__ __launch_bounds__(256) void k_head(
    const short* __restrict__ hS, const short* __restrict__ wSs1,
    const float* __restrict__ g1, const float* __restrict__ b1,
    const float* __restrict__ w2, const float* __restrict__ b2,
    float* __restrict__ out)
{
    __shared__ short wLDS[3][64 * 80];
    __shared__ float partS[16][4];

    int t  = threadIdx.x;
    int p0 = blockIdx.x * 16;

#pragma unroll
    for (int it = 0; it < 6; ++it) {
        int f = it * 256 + t;
        int plane = f >> 9, i8 = f & 511;
        int o = i8 >> 3, c8 = i8 & 7;
        uint4 v = ((const uint4*)(wSs1 + (size_t)plane * 4096))[i8];
        *(uint4*)&wLDS[plane][o * 80 + c8 * 8] = v;
    }
    __syncthreads();

    int wv = t >> 6, lane = t & 63, col = lane & 15, quad = lane >> 4;

    const short* crow = hS + (size_t)(p0 + col) * Hh;
    f32x4 acc = (f32x4){0.f, 0.f, 0.f, 0.f};
#pragma unroll
    for (int ks = 0; ks < 2; ++ks) {
        int aoff = ks * 32 + quad * 8;
        bf16x8 AH = *(const bf16x8*)(crow + 0 * PLN + aoff);
        bf16x8 AM = *(const bf16x8*)(crow + 1 * PLN + aoff);
        bf16x8 AL = *(const bf16x8*)(crow + 2 * PLN + aoff);
        int boff = (wv * 16 + col) * 80 + aoff;
        bf16x8 BH = *(bf16x8*)&wLDS[0][boff];
        bf16x8 BM = *(bf16x8*)&wLDS[1][boff];
        bf16x8 BL = *(bf16x8*)&wLDS[2][boff];
        MFMA6(acc, AH, AM, AL, BH, BM, BL)
    }

    int o = wv * 16 + col;
    const float inv = rsqrtf(1.0f + EPSf);
    float sc = g1[o] * inv, bo = b1[o], w2o = w2[o];
    float s4[4];
#pragma unroll
    for (int r = 0; r < 4; ++r) {
        float a = fmaxf(fmaf(acc[r], sc, bo), 0.0f);
        s4[r] = a * w2o;
    }
#pragma unroll
    for (int sh = 1; sh < 16; sh <<= 1) {
#pragma unroll
        for (int r = 0; r < 4; ++r) s4[r] += __shfl_xor(s4[r], sh, 64);
    }
    if (col == 0) {
#pragma unroll
        for (int r = 0; r < 4; ++r) partS[quad * 4 + r][wv] = s4[r];
    }
    __syncthreads();
    if (t < 16)
        out[p0 + t] = partS[t][0] + partS[t][1] + partS[t][2] + partS[t][3] + b2[0];
}

// ---------------------------------------------------------------------------
extern "C" void kernel_launch(void* const* d_in, const int* in_sizes, int n_in,
                              void* d_out, int out_size, void* d_ws, size_t ws_size,
                              hipStream_t stream)
{
    const float* x    = (const float*)d_in[0];
    const float* w_t1 = (const float*)d_in[1];
    const float* g_t1 = (const float*)d_in[2];
    const float* b_t1 = (const float*)d_in[3];
    const float* w_t2 = (const float*)d_in[4];
    const float* g_t2 = (const float*)d_in[5];
    const float* b_t2 = (const float*)d_in[6];
    const float* w_nb = (const float*)d_in[7];
    const float* g_nb = (const float*)d_in[8];
    const float* b_nb = (const float*)d_in[9];
    const float* w_s1 = (const float*)d_in[10];
    const float* g_s1 = (const float*)d_in[11];
    const float* b_s1 = (const float*)d_in[12];
    const float* w_s2 = (const float*)d_in[13];
    const float* b_s2 = (const float*)d_in[14];
    float* out = (float*)d_out;

    float* sq  = (float*)d_ws;
    int*   idx = (int*)(sq + (size_t)Bn * Nn);
    short* hSa = (short*)(idx + (size_t)Bn * Nn * Kk);
    short* hSb = hSa + 3 * PLN;
    short* wS  = hSb + 3 * PLN;            // 18 planes x 4096 shorts

    k_prep<<<64, 256, 0, stream>>>(w_nb, w_t2, w_s1, wS);
    k_t12<<<Bn * Nn / 16, 256, 0, stream>>>(x, w_t1, g_t1, b_t1,
                                            wS + (size_t)12 * 4096, g_t2, b_t2,
                                            hSa, sq);

    const short* hSin = hSa;
    short* hSout = hSb;
    for (int r = 0; r < Rr; ++r) {
        k_knn<<<Bn * (Nn / 16), 256, 0, stream>>>(hSin, sq, idx);
        k_edge<<<Bn * Nn / 16, 256, 0, stream>>>(hSin, idx,
            wS + (size_t)r * 6 * 4096, g_nb + r * Hh, b_nb + r * Hh,
            hSout, sq);
        const short* ts = hSout; hSout = (short*)hSin; hSin = ts;
    }
    k_head<<<Bn * Nn / 16, 256, 0, stream>>>(hSin, wS + (size_t)15 * 4096,
                                             g_s1, b_s1, w_s2, b_s2, out);
}

// Round 11
// 478.641 us; speedup vs baseline: 1.9058x; 1.0002x over previous
//
#include <hip/hip_runtime.h>
#include <math.h>

#define Bn 128
#define Nn 512
#define Cc 7
#define Hh 64
#define Kk 16
#define Rr 2
#define EPSf 1e-5f

typedef __attribute__((ext_vector_type(8))) short bf16x8;
typedef __attribute__((ext_vector_type(4))) float f32x4;

#define PLN ((size_t)4194304)   // elements per h-split plane (B*N*H)

// exact truncation split: a = hi + mid + lo + r, |r| <= 2^-24 |a|
__device__ __forceinline__ void split3(float a, short &hs, short &ms, short &ls) {
    unsigned u  = __float_as_uint(a);
    unsigned hu = u & 0xFFFF0000u;
    float r1 = a - __uint_as_float(hu);
    unsigned mu = __float_as_uint(r1) & 0xFFFF0000u;
    float r2 = r1 - __uint_as_float(mu);
    unsigned lu = __float_as_uint(r2) & 0xFFFF0000u;
    hs = (short)(hu >> 16); ms = (short)(mu >> 16); ls = (short)(lu >> 16);
}

#define MFMA6(acc, AH, AM, AL, BH, BM, BL) \
    acc = __builtin_amdgcn_mfma_f32_16x16x32_bf16(AL, BH, acc, 0, 0, 0); \
    acc = __builtin_amdgcn_mfma_f32_16x16x32_bf16(AM, BM, acc, 0, 0, 0); \
    acc = __builtin_amdgcn_mfma_f32_16x16x32_bf16(AH, BL, acc, 0, 0, 0); \
    acc = __builtin_amdgcn_mfma_f32_16x16x32_bf16(AM, BH, acc, 0, 0, 0); \
    acc = __builtin_amdgcn_mfma_f32_16x16x32_bf16(AH, BM, acc, 0, 0, 0); \
    acc = __builtin_amdgcn_mfma_f32_16x16x32_bf16(AH, BH, acc, 0, 0, 0);

// ---------------------------------------------------------------------------
// prep: split weights into bf16x3 planes.
// wS layout (4096-short planes): [r0: wd x3, wcd x3][r1: wd x3, wcd x3]
//                                [w_t2 x3][w_s1 x3]   (18 planes total)
// ---------------------------------------------------------------------------
__global__ void k_prep(const float* __restrict__ w_nb, const float* __restrict__ w_t2,
                       const float* __restrict__ w_s1, short* __restrict__ wS)
{
    int i = blockIdx.x * 256 + threadIdx.x;     // 0 .. 16383
    short h_, m_, l_;
    if (i < 8192) {
        int r = i >> 12, oc = i & 4095;
        int o = oc >> 6, c = oc & 63;
        const float* wr = w_nb + (size_t)r * Hh * 2 * Hh + (size_t)o * 2 * Hh;
        float wc = wr[c], wd = wr[Hh + c];
        short* base = wS + (size_t)r * 6 * 4096;
        split3(wd, h_, m_, l_);
        base[0 * 4096 + oc] = h_; base[1 * 4096 + oc] = m_; base[2 * 4096 + oc] = l_;
        split3(wc - wd, h_, m_, l_);
        base[3 * 4096 + oc] = h_; base[4 * 4096 + oc] = m_; base[5 * 4096 + oc] = l_;
    } else {
        int which = (i - 8192) >> 12;            // 0: w_t2, 1: w_s1
        int oc = i & 4095;
        const float* src = which ? w_s1 : w_t2;
        short* base = wS + (size_t)(12 + which * 3) * 4096;
        split3(src[oc], h_, m_, l_);
        base[0 * 4096 + oc] = h_; base[1 * 4096 + oc] = m_; base[2 * 4096 + oc] = l_;
    }
}

// ---------------------------------------------------------------------------
// t1 + t2: layer 1 fp32 VALU (bit-exact), layer 2 via MFMA6 from split planes.
// ---------------------------------------------------------------------------
__global__ __launch_bounds__(256) void k_t12(
    const float* __restrict__ x,
    const float* __restrict__ w1, const float* __restrict__ g1, const float* __restrict__ b1,
    const short* __restrict__ wS2, const float* __restrict__ g2, const float* __restrict__ b2,
    short* __restrict__ hS, float* __restrict__ sq)
{
    __shared__ short wLDS[3][64 * 80];
    __shared__ short h1S[3][16 * 80];
    __shared__ float sqP[16][4];

    int t  = threadIdx.x;
    int p0 = blockIdx.x * 16;
    int b  = p0 >> 9, n0 = p0 & 511;

#pragma unroll
    for (int it = 0; it < 6; ++it) {
        int f = it * 256 + t;
        int plane = f >> 9, i8 = f & 511;
        int o = i8 >> 3, c8 = i8 & 7;
        uint4 v = ((const uint4*)(wS2 + (size_t)plane * 4096))[i8];
        *(uint4*)&wLDS[plane][o * 80 + c8 * 8] = v;
    }

    {
        int pt = t & 15, ow = t >> 4;
        const float inv = rsqrtf(1.0f + EPSf);
        float xv[Cc];
#pragma unroll
        for (int c = 0; c < Cc; ++c)
            xv[c] = x[(b * Cc + c) * Nn + n0 + pt];
#pragma unroll
        for (int j = 0; j < 4; ++j) {
            int o = ow + 16 * j;
            float acc = 0.0f;
#pragma unroll
            for (int c = 0; c < Cc; ++c)
                acc = fmaf(w1[o * Cc + c], xv[c], acc);
            acc = fmaf(acc, g1[o] * inv, b1[o]);
            acc = fmaxf(acc, 0.0f);
            short hs_, ms_, ls_;
            split3(acc, hs_, ms_, ls_);
            h1S[0][pt * 80 + o] = hs_;
            h1S[1][pt * 80 + o] = ms_;
            h1S[2][pt * 80 + o] = ls_;
        }
    }
    __syncthreads();

    int wv = t >> 6, lane = t & 63, col = lane & 15, quad = lane >> 4;
    const float inv = rsqrtf(1.0f + EPSf);

    f32x4 acc = (f32x4){0.f, 0.f, 0.f, 0.f};
#pragma unroll
    for (int ks = 0; ks < 2; ++ks) {
        int aoff = ks * 32 + quad * 8;
        bf16x8 AH = *(bf16x8*)&h1S[0][col * 80 + aoff];
        bf16x8 AM = *(bf16x8*)&h1S[1][col * 80 + aoff];
        bf16x8 AL = *(bf16x8*)&h1S[2][col * 80 + aoff];
        int boff = (wv * 16 + col) * 80 + aoff;
        bf16x8 BH = *(bf16x8*)&wLDS[0][boff];
        bf16x8 BM = *(bf16x8*)&wLDS[1][boff];
        bf16x8 BL = *(bf16x8*)&wLDS[2][boff];
        MFMA6(acc, AH, AM, AL, BH, BM, BL)
    }

    int o = wv * 16 + col;
    float sc = g2[o] * inv, bo = b2[o];
    float s4[4];
#pragma unroll
    for (int r = 0; r < 4; ++r) {
        int pt = quad * 4 + r;
        float a2 = fmaf(acc[r], sc, bo);
        a2 = fmaxf(a2, 0.0f);
        short hs_, ms_, ls_;
        split3(a2, hs_, ms_, ls_);
        size_t rowp = (size_t)(p0 + pt) * Hh + o;
        hS[0 * PLN + rowp] = hs_;
        hS[1 * PLN + rowp] = ms_;
        hS[2 * PLN + rowp] = ls_;
        s4[r] = a2 * a2;
    }
#pragma unroll
    for (int sh = 1; sh < 16; sh <<= 1) {
#pragma unroll
        for (int r = 0; r < 4; ++r) s4[r] += __shfl_xor(s4[r], sh, 64);
    }
    if (col == 0) {
#pragma unroll
        for (int r = 0; r < 4; ++r) sqP[quad * 4 + r][wv] = s4[r];
    }
    __syncthreads();
    if (t < 16) sq[p0 + t] = sqP[t][0] + sqP[t][1] + sqP[t][2] + sqP[t][3];
}

// ---------------------------------------------------------------------------
// kNN: Gram via MFMA + XCD swizzle. Selection: 4 chains/wave; min all-reduce
// is now pure DPP (xor1, xor2, ror4, ror8, row_bcast15, row_bcast31) +
// readlane(63) — ZERO DS ops in the serial chain. Same keys, same tie-break
// (ballot-ffs lane-major) -> bit-identical indices to round 10.
// ---------------------------------------------------------------------------
__global__ __launch_bounds__(256) void k_knn(
    const short* __restrict__ hS, const float* __restrict__ sq, int* __restrict__ idxout)
{
    int xcd = blockIdx.x & 7;
    int s_  = blockIdx.x >> 3;
    int b   = xcd + ((s_ >> 5) << 3);
    int n0  = (s_ & 31) << 4;
    int t   = threadIdx.x;

    __shared__ unsigned int keysLDS[16 * 512];
    __shared__ float sqS[512];

    if (t < 128) ((float4*)sqS)[t] = ((const float4*)(sq + (size_t)b * Nn))[t];
    __syncthreads();

    int wv = t >> 6, lane = t & 63, col = lane & 15, quad = lane >> 4;
    const size_t rowbase = (size_t)b * Nn * Hh;

    bf16x8 AH[2], AM[2], AL[2];
    {
        const short* crow = hS + rowbase + (size_t)(n0 + col) * Hh;
#pragma unroll
        for (int ks = 0; ks < 2; ++ks) {
            int aoff = ks * 32 + quad * 8;
            AH[ks] = *(const bf16x8*)(crow + 0 * PLN + aoff);
            AM[ks] = *(const bf16x8*)(crow + 1 * PLN + aoff);
            AL[ks] = *(const bf16x8*)(crow + 2 * PLN + aoff);
        }
    }
    float sqcr[4];
#pragma unroll
    for (int r_ = 0; r_ < 4; ++r_) sqcr[r_] = sqS[n0 + quad * 4 + r_];

    for (int i = 0; i < 8; ++i) {
        int nt = wv * 8 + i;
        const short* prow = hS + rowbase + (size_t)(nt * 16 + col) * Hh;
        f32x4 acc = (f32x4){0.f, 0.f, 0.f, 0.f};
#pragma unroll
        for (int ks = 0; ks < 2; ++ks) {
            int aoff = ks * 32 + quad * 8;
            bf16x8 BH = *(const bf16x8*)(prow + 0 * PLN + aoff);
            bf16x8 BM = *(const bf16x8*)(prow + 1 * PLN + aoff);
            bf16x8 BL = *(const bf16x8*)(prow + 2 * PLN + aoff);
            MFMA6(acc, AH[ks], AM[ks], AL[ks], BH, BM, BL)
        }
        float sqp = sqS[nt * 16 + col];
#pragma unroll
        for (int r_ = 0; r_ < 4; ++r_) {
            int ctr = quad * 4 + r_;
            float d = sqcr[r_] + sqp - 2.0f * acc[r_];
            unsigned int u = __float_as_uint(d);
            u = ((int)u < 0) ? ~u : (u | 0x80000000u);
            keysLDS[ctr * 512 + nt * 16 + col] = u;
        }
    }
    __syncthreads();

    unsigned int kk[4][8];
    int rr[4][8];
#pragma unroll
    for (int s = 0; s < 4; ++s) {
        int jj = wv * 4 + s;
        const uint4* kp = (const uint4*)&keysLDS[jj * 512 + (lane << 3)];
        uint4 A = kp[0], Bq = kp[1];
        kk[s][0] = A.x;  kk[s][1] = A.y;  kk[s][2] = A.z;  kk[s][3] = A.w;
        kk[s][4] = Bq.x; kk[s][5] = Bq.y; kk[s][6] = Bq.z; kk[s][7] = Bq.w;
#pragma unroll
        for (int q = 0; q < 8; ++q) rr[s][q] = q;
    }

#define CE(s, i, j_) { \
    bool sw = (kk[s][i] > kk[s][j_]) || (kk[s][i] == kk[s][j_] && rr[s][i] > rr[s][j_]); \
    unsigned int tk = sw ? kk[s][i] : kk[s][j_]; kk[s][i] = sw ? kk[s][j_] : kk[s][i]; kk[s][j_] = tk; \
    int tr = sw ? rr[s][i] : rr[s][j_]; rr[s][i] = sw ? rr[s][j_] : rr[s][i]; rr[s][j_] = tr; }
#pragma unroll
    for (int s = 0; s < 4; ++s) {
        CE(s,0,1) CE(s,2,3) CE(s,4,5) CE(s,6,7)
        CE(s,0,2) CE(s,1,3) CE(s,4,6) CE(s,5,7)
        CE(s,1,2) CE(s,5,6)
        CE(s,0,4) CE(s,1,5) CE(s,2,6) CE(s,3,7)
        CE(s,2,4) CE(s,3,5)
        CE(s,1,2) CE(s,3,4) CE(s,5,6)
    }
#undef CE

    int outbase[4];
#pragma unroll
    for (int s = 0; s < 4; ++s) outbase[s] = (b * Nn + n0 + wv * 4 + s) * Kk;

    for (int iter = 0; iter < Kk; ++iter) {
        unsigned int mv[4];
#pragma unroll
        for (int s = 0; s < 4; ++s) mv[s] = kk[s][0];
        // pure-DPP 64-lane min all-reduce; full min lands in lanes 48-63
#define DSTEP(ctrl) { \
        _Pragma("unroll") \
        for (int s = 0; s < 4; ++s) { \
            unsigned int ov = (unsigned int)__builtin_amdgcn_update_dpp((int)mv[s], (int)mv[s], ctrl, 0xF, 0xF, false); \
            mv[s] = (ov < mv[s]) ? ov : mv[s]; } }
        DSTEP(0xB1)    // quad_perm xor1
        DSTEP(0x4E)    // quad_perm xor2
        DSTEP(0x124)   // row_ror:4
        DSTEP(0x128)   // row_ror:8     -> each row16 uniform
        DSTEP(0x142)   // row_bcast15   -> rows 1,3 pick up rows 0,2
        DSTEP(0x143)   // row_bcast31   -> rows 2,3 pick up min(r0,r1); lane63 full
#undef DSTEP
        unsigned int m[4];
#pragma unroll
        for (int s = 0; s < 4; ++s)
            m[s] = (unsigned int)__builtin_amdgcn_readlane((int)mv[s], 63);
#pragma unroll
        for (int s = 0; s < 4; ++s) {
            unsigned long long bal = __ballot(kk[s][0] == m[s]);
            int wn = __ffsll(bal) - 1;
            if (lane == wn) {
                idxout[outbase[s] + iter] = (lane << 3) + rr[s][0];
#pragma unroll
                for (int q = 0; q < 7; ++q) { kk[s][q] = kk[s][q + 1]; rr[s][q] = rr[s][q + 1]; }
                kk[s][7] = 0xFFFFFFFFu;
            }
        }
    }
}

// ---------------------------------------------------------------------------
// EdgeConv via MFMA, base/delta, XCD swizzle (unchanged from round 10)
// ---------------------------------------------------------------------------
__global__ __launch_bounds__(256, 4) void k_edge(
    const short* __restrict__ hS,
    const int* __restrict__ idx,
    const short* __restrict__ wS,
    const float* __restrict__ g, const float* __restrict__ bb_,
    short* __restrict__ hSout, float* __restrict__ sqout)
{
    __shared__ short wLDS[3][64 * 72];
    __shared__ float baseS[16 * 68];
    __shared__ int   idxS[256];

    int t   = threadIdx.x;
    int xcd = blockIdx.x & 7;
    int s_  = blockIdx.x >> 3;
    int b   = xcd + ((s_ >> 5) << 3);
    int p0  = b * Nn + ((s_ & 31) << 4);

    idxS[t] = idx[p0 * Kk + t];
#pragma unroll
    for (int it = 0; it < 6; ++it) {
        int f = it * 256 + t;
        int plane = f >> 9;
        int i8 = f & 511;
        int o = i8 >> 3, c8 = i8 & 7;
        uint4 v = ((const uint4*)(wS + (size_t)(3 + plane) * 4096))[i8];
        *(uint4*)&wLDS[plane][o * 72 + c8 * 8] = v;
    }
    __syncthreads();

    int wv = t >> 6, lane = t & 63, col = lane & 15, quad = lane >> 4;

    {
        f32x4 bacc = (f32x4){0.f, 0.f, 0.f, 0.f};
        const short* hrow = hS + (size_t)(p0 + col) * Hh;
#pragma unroll
        for (int ks = 0; ks < 2; ++ks) {
            int aoff = ks * 32 + quad * 8;
            bf16x8 AH = *(const bf16x8*)(hrow + 0 * PLN + aoff);
            bf16x8 AM = *(const bf16x8*)(hrow + 1 * PLN + aoff);
            bf16x8 AL = *(const bf16x8*)(hrow + 2 * PLN + aoff);
            int boff = (wv * 16 + col) * 72 + aoff;
            bf16x8 BH = *(bf16x8*)&wLDS[0][boff];
            bf16x8 BM = *(bf16x8*)&wLDS[1][boff];
            bf16x8 BL = *(bf16x8*)&wLDS[2][boff];
            MFMA6(bacc, AH, AM, AL, BH, BM, BL)
        }
#pragma unroll
        for (int r_ = 0; r_ < 4; ++r_)
            baseS[(quad * 4 + r_) * 68 + wv * 16 + col] = bacc[r_];
    }
    __syncthreads();

#pragma unroll
    for (int it = 0; it < 6; ++it) {
        int f = it * 256 + t;
        int plane = f >> 9;
        int i8 = f & 511;
        int o = i8 >> 3, c8 = i8 & 7;
        uint4 v = ((const uint4*)(wS + (size_t)plane * 4096))[i8];
        *(uint4*)&wLDS[plane][o * 72 + c8 * 8] = v;
    }
    __syncthreads();

    const float inv = rsqrtf(1.0f + EPSf);
    float scv[4], bov[4];
#pragma unroll
    for (int nt = 0; nt < 4; ++nt) {
        scv[nt] = g[nt * 16 + col] * inv;
        bov[nt] = bb_[nt * 16 + col];
    }

    for (int pr = 0; pr < 2; ++pr) {
        bf16x8 A[2][2][3];
#pragma unroll
        for (int pt2 = 0; pt2 < 2; ++pt2) {
            int pl = wv * 4 + pr * 2 + pt2;
            int j = idxS[pl * 16 + col];
            const short* nrow = hS + ((size_t)(b * Nn) + j) * Hh;
#pragma unroll
            for (int ks = 0; ks < 2; ++ks) {
                int aoff = ks * 32 + quad * 8;
                A[pt2][ks][0] = *(const bf16x8*)(nrow + 0 * PLN + aoff);
                A[pt2][ks][1] = *(const bf16x8*)(nrow + 1 * PLN + aoff);
                A[pt2][ks][2] = *(const bf16x8*)(nrow + 2 * PLN + aoff);
            }
        }

        f32x4 acc[2][4];
#pragma unroll
        for (int pt2 = 0; pt2 < 2; ++pt2)
#pragma unroll
            for (int nt = 0; nt < 4; ++nt)
                acc[pt2][nt] = (f32x4){0.f, 0.f, 0.f, 0.f};

#pragma unroll
        for (int ks = 0; ks < 2; ++ks)
#pragma unroll
            for (int nt = 0; nt < 4; ++nt) {
                int boff = (nt * 16 + col) * 72 + ks * 32 + quad * 8;
                bf16x8 BH = *(bf16x8*)&wLDS[0][boff];
                bf16x8 BM = *(bf16x8*)&wLDS[1][boff];
                bf16x8 BL = *(bf16x8*)&wLDS[2][boff];
#pragma unroll
                for (int pt2 = 0; pt2 < 2; ++pt2) {
                    f32x4 a = acc[pt2][nt];
                    MFMA6(a, A[pt2][ks][0], A[pt2][ks][1], A[pt2][ks][2], BH, BM, BL)
                    acc[pt2][nt] = a;
                }
            }

#pragma unroll
        for (int pt2 = 0; pt2 < 2; ++pt2) {
            int pl = wv * 4 + pr * 2 + pt2;
            int pglob = p0 + pl;
            float res[4];
#pragma unroll
            for (int nt = 0; nt < 4; ++nt) {
                float base = baseS[pl * 68 + nt * 16 + col];
                f32x4 a = acc[pt2][nt];
                float v0 = fmaf(base + a[0], scv[nt], bov[nt]);
                float v1 = fmaf(base + a[1], scv[nt], bov[nt]);
                float v2 = fmaf(base + a[2], scv[nt], bov[nt]);
                float v3 = fmaf(base + a[3], scv[nt], bov[nt]);
                float vm = fmaxf(fmaxf(v0, v1), fmaxf(v2, v3));
                vm = fmaxf(vm, __shfl_xor(vm, 16));
                vm = fmaxf(vm, __shfl_xor(vm, 32));
                res[nt] = fmaxf(vm, 0.0f);
            }
            float rv = res[quad];
            short hs_, ms_, ls_;
            split3(rv, hs_, ms_, ls_);
            hSout[0 * PLN + (size_t)pglob * Hh + lane] = hs_;
            hSout[1 * PLN + (size_t)pglob * Hh + lane] = ms_;
            hSout[2 * PLN + (size_t)pglob * Hh + lane] = ls_;

            float s = res[0] * res[0] + res[1] * res[1]
                    + res[2] * res[2] + res[3] * res[3];
            s += __shfl_xor(s, 1);
            s += __shfl_xor(s, 2);
            s += __shfl_xor(s, 4);
            s += __shfl_xor(s, 8);
            if (lane == 0) sqout[pglob] = s;
        }
    }
}

// ---------------------------------------------------------------------------
// head via MFMA (unchanged from round 10)
// ---------------------------------------------------------------------------
__global__ __launch_bounds__(256) void k_head(
    const short* __restrict__ hS, const short* __restrict__ wSs1,
    const float* __restrict__ g1, const float* __restrict__ b1,
    const float* __restrict__ w2, const float* __restrict__ b2,
    float* __restrict__ out)
{
    __shared__ short wLDS[3][64 * 80];
    __shared__ float partS[16][4];

    int t  = threadIdx.x;
    int p0 = blockIdx.x * 16;

#pragma unroll
    for (int it = 0; it < 6; ++it) {
        int f = it * 256 + t;
        int plane = f >> 9, i8 = f & 511;
        int o = i8 >> 3, c8 = i8 & 7;
        uint4 v = ((const uint4*)(wSs1 + (size_t)plane * 4096))[i8];
        *(uint4*)&wLDS[plane][o * 80 + c8 * 8] = v;
    }
    __syncthreads();

    int wv = t >> 6, lane = t & 63, col = lane & 15, quad = lane >> 4;

    const short* crow = hS + (size_t)(p0 + col) * Hh;
    f32x4 acc = (f32x4){0.f, 0.f, 0.f, 0.f};
#pragma unroll
    for (int ks = 0; ks < 2; ++ks) {
        int aoff = ks * 32 + quad * 8;
        bf16x8 AH = *(const bf16x8*)(crow + 0 * PLN + aoff);
        bf16x8 AM = *(const bf16x8*)(crow + 1 * PLN + aoff);
        bf16x8 AL = *(const bf16x8*)(crow + 2 * PLN + aoff);
        int boff = (wv * 16 + col) * 80 + aoff;
        bf16x8 BH = *(bf16x8*)&wLDS[0][boff];
        bf16x8 BM = *(bf16x8*)&wLDS[1][boff];
        bf16x8 BL = *(bf16x8*)&wLDS[2][boff];
        MFMA6(acc, AH, AM, AL, BH, BM, BL)
    }

    int o = wv * 16 + col;
    const float inv = rsqrtf(1.0f + EPSf);
    float sc = g1[o] * inv, bo = b1[o], w2o = w2[o];
    float s4[4];
#pragma unroll
    for (int r = 0; r < 4; ++r) {
        float a = fmaxf(fmaf(acc[r], sc, bo), 0.0f);
        s4[r] = a * w2o;
    }
#pragma unroll
    for (int sh = 1; sh < 16; sh <<= 1) {
#pragma unroll
        for (int r = 0; r < 4; ++r) s4[r] += __shfl_xor(s4[r], sh, 64);
    }
    if (col == 0) {
#pragma unroll
        for (int r = 0; r < 4; ++r) partS[quad * 4 + r][wv] = s4[r];
    }
    __syncthreads();
    if (t < 16)
        out[p0 + t] = partS[t][0] + partS[t][1] + partS[t][2] + partS[t][3] + b2[0];
}

// ---------------------------------------------------------------------------
extern "C" void kernel_launch(void* const* d_in, const int* in_sizes, int n_in,
                              void* d_out, int out_size, void* d_ws, size_t ws_size,
                              hipStream_t stream)
{
    const float* x    = (const float*)d_in[0];
    const float* w_t1 = (const float*)d_in[1];
    const float* g_t1 = (const float*)d_in[2];
    const float* b_t1 = (const float*)d_in[3];
    const float* w_t2 = (const float*)d_in[4];
    const float* g_t2 = (const float*)d_in[5];
    const float* b_t2 = (const float*)d_in[6];
    const float* w_nb = (const float*)d_in[7];
    const float* g_nb = (const float*)d_in[8];
    const float* b_nb = (const float*)d_in[9];
    const float* w_s1 = (const float*)d_in[10];
    const float* g_s1 = (const float*)d_in[11];
    const float* b_s1 = (const float*)d_in[12];
    const float* w_s2 = (const float*)d_in[13];
    const float* b_s2 = (const float*)d_in[14];
    float* out = (float*)d_out;

    float* sq  = (float*)d_ws;
    int*   idx = (int*)(sq + (size_t)Bn * Nn);
    short* hSa = (short*)(idx + (size_t)Bn * Nn * Kk);
    short* hSb = hSa + 3 * PLN;
    short* wS  = hSb + 3 * PLN;            // 18 planes x 4096 shorts

    k_prep<<<64, 256, 0, stream>>>(w_nb, w_t2, w_s1, wS);
    k_t12<<<Bn * Nn / 16, 256, 0, stream>>>(x, w_t1, g_t1, b_t1,
                                            wS + (size_t)12 * 4096, g_t2, b_t2,
                                            hSa, sq);

    const short* hSin = hSa;
    short* hSout = hSb;
    for (int r = 0; r < Rr; ++r) {
        k_knn<<<Bn * (Nn / 16), 256, 0, stream>>>(hSin, sq, idx);
        k_edge<<<Bn * Nn / 16, 256, 0, stream>>>(hSin, idx,
            wS + (size_t)r * 6 * 4096, g_nb + r * Hh, b_nb + r * Hh,
            hSout, sq);
        const short* ts = hSout; hSout = (short*)hSin; hSin = ts;
    }
    k_head<<<Bn * Nn / 16, 256, 0, stream>>>(hSin, wS + (size_t)15 * 4096,
                                             g_s1, b_s1, w_s2, b_s2, out);
}

// Round 12
// 474.125 us; speedup vs baseline: 1.9240x; 1.0095x over previous
//
#include <hip/hip_runtime.h>
#include <math.h>

#define Bn 128
#define Nn 512
#define Cc 7
#define Hh 64
#define Kk 16
#define Rr 2
#define EPSf 1e-5f

typedef __attribute__((ext_vector_type(8))) short bf16x8;
typedef __attribute__((ext_vector_type(4))) float f32x4;

#define PLN ((size_t)4194304)   // elements per h-split plane (B*N*H)

// exact truncation split: a = hi + mid + lo + r, |r| <= 2^-24 |a|
__device__ __forceinline__ void split3(float a, short &hs, short &ms, short &ls) {
    unsigned u  = __float_as_uint(a);
    unsigned hu = u & 0xFFFF0000u;
    float r1 = a - __uint_as_float(hu);
    unsigned mu = __float_as_uint(r1) & 0xFFFF0000u;
    float r2 = r1 - __uint_as_float(mu);
    unsigned lu = __float_as_uint(r2) & 0xFFFF0000u;
    hs = (short)(hu >> 16); ms = (short)(mu >> 16); ls = (short)(lu >> 16);
}

#define MFMA6(acc, AH, AM, AL, BH, BM, BL) \
    acc = __builtin_amdgcn_mfma_f32_16x16x32_bf16(AL, BH, acc, 0, 0, 0); \
    acc = __builtin_amdgcn_mfma_f32_16x16x32_bf16(AM, BM, acc, 0, 0, 0); \
    acc = __builtin_amdgcn_mfma_f32_16x16x32_bf16(AH, BL, acc, 0, 0, 0); \
    acc = __builtin_amdgcn_mfma_f32_16x16x32_bf16(AM, BH, acc, 0, 0, 0); \
    acc = __builtin_amdgcn_mfma_f32_16x16x32_bf16(AH, BM, acc, 0, 0, 0); \
    acc = __builtin_amdgcn_mfma_f32_16x16x32_bf16(AH, BH, acc, 0, 0, 0);

// ---------------------------------------------------------------------------
// prep: split weights into bf16x3 planes.
// wS layout (4096-short planes): [r0: wd x3, wcd x3][r1: wd x3, wcd x3]
//                                [w_t2 x3][w_s1 x3]   (18 planes total)
// ---------------------------------------------------------------------------
__global__ void k_prep(const float* __restrict__ w_nb, const float* __restrict__ w_t2,
                       const float* __restrict__ w_s1, short* __restrict__ wS)
{
    int i = blockIdx.x * 256 + threadIdx.x;     // 0 .. 16383
    short h_, m_, l_;
    if (i < 8192) {
        int r = i >> 12, oc = i & 4095;
        int o = oc >> 6, c = oc & 63;
        const float* wr = w_nb + (size_t)r * Hh * 2 * Hh + (size_t)o * 2 * Hh;
        float wc = wr[c], wd = wr[Hh + c];
        short* base = wS + (size_t)r * 6 * 4096;
        split3(wd, h_, m_, l_);
        base[0 * 4096 + oc] = h_; base[1 * 4096 + oc] = m_; base[2 * 4096 + oc] = l_;
        split3(wc - wd, h_, m_, l_);
        base[3 * 4096 + oc] = h_; base[4 * 4096 + oc] = m_; base[5 * 4096 + oc] = l_;
    } else {
        int which = (i - 8192) >> 12;            // 0: w_t2, 1: w_s1
        int oc = i & 4095;
        const float* src = which ? w_s1 : w_t2;
        short* base = wS + (size_t)(12 + which * 3) * 4096;
        split3(src[oc], h_, m_, l_);
        base[0 * 4096 + oc] = h_; base[1 * 4096 + oc] = m_; base[2 * 4096 + oc] = l_;
    }
}

// ---------------------------------------------------------------------------
// t1 + t2: layer 1 fp32 VALU (bit-exact), layer 2 via MFMA6 from split planes.
// ---------------------------------------------------------------------------
__global__ __launch_bounds__(256) void k_t12(
    const float* __restrict__ x,
    const float* __restrict__ w1, const float* __restrict__ g1, const float* __restrict__ b1,
    const short* __restrict__ wS2, const float* __restrict__ g2, const float* __restrict__ b2,
    short* __restrict__ hS, float* __restrict__ sq)
{
    __shared__ short wLDS[3][64 * 80];
    __shared__ short h1S[3][16 * 80];
    __shared__ float sqP[16][4];

    int t  = threadIdx.x;
    int p0 = blockIdx.x * 16;
    int b  = p0 >> 9, n0 = p0 & 511;

#pragma unroll
    for (int it = 0; it < 6; ++it) {
        int f = it * 256 + t;
        int plane = f >> 9, i8 = f & 511;
        int o = i8 >> 3, c8 = i8 & 7;
        uint4 v = ((const uint4*)(wS2 + (size_t)plane * 4096))[i8];
        *(uint4*)&wLDS[plane][o * 80 + c8 * 8] = v;
    }

    {
        int pt = t & 15, ow = t >> 4;
        const float inv = rsqrtf(1.0f + EPSf);
        float xv[Cc];
#pragma unroll
        for (int c = 0; c < Cc; ++c)
            xv[c] = x[(b * Cc + c) * Nn + n0 + pt];
#pragma unroll
        for (int j = 0; j < 4; ++j) {
            int o = ow + 16 * j;
            float acc = 0.0f;
#pragma unroll
            for (int c = 0; c < Cc; ++c)
                acc = fmaf(w1[o * Cc + c], xv[c], acc);
            acc = fmaf(acc, g1[o] * inv, b1[o]);
            acc = fmaxf(acc, 0.0f);
            short hs_, ms_, ls_;
            split3(acc, hs_, ms_, ls_);
            h1S[0][pt * 80 + o] = hs_;
            h1S[1][pt * 80 + o] = ms_;
            h1S[2][pt * 80 + o] = ls_;
        }
    }
    __syncthreads();

    int wv = t >> 6, lane = t & 63, col = lane & 15, quad = lane >> 4;
    const float inv = rsqrtf(1.0f + EPSf);

    f32x4 acc = (f32x4){0.f, 0.f, 0.f, 0.f};
#pragma unroll
    for (int ks = 0; ks < 2; ++ks) {
        int aoff = ks * 32 + quad * 8;
        bf16x8 AH = *(bf16x8*)&h1S[0][col * 80 + aoff];
        bf16x8 AM = *(bf16x8*)&h1S[1][col * 80 + aoff];
        bf16x8 AL = *(bf16x8*)&h1S[2][col * 80 + aoff];
        int boff = (wv * 16 + col) * 80 + aoff;
        bf16x8 BH = *(bf16x8*)&wLDS[0][boff];
        bf16x8 BM = *(bf16x8*)&wLDS[1][boff];
        bf16x8 BL = *(bf16x8*)&wLDS[2][boff];
        MFMA6(acc, AH, AM, AL, BH, BM, BL)
    }

    int o = wv * 16 + col;
    float sc = g2[o] * inv, bo = b2[o];
    float s4[4];
#pragma unroll
    for (int r = 0; r < 4; ++r) {
        int pt = quad * 4 + r;
        float a2 = fmaf(acc[r], sc, bo);
        a2 = fmaxf(a2, 0.0f);
        short hs_, ms_, ls_;
        split3(a2, hs_, ms_, ls_);
        size_t rowp = (size_t)(p0 + pt) * Hh + o;
        hS[0 * PLN + rowp] = hs_;
        hS[1 * PLN + rowp] = ms_;
        hS[2 * PLN + rowp] = ls_;
        s4[r] = a2 * a2;
    }
#pragma unroll
    for (int sh = 1; sh < 16; sh <<= 1) {
#pragma unroll
        for (int r = 0; r < 4; ++r) s4[r] += __shfl_xor(s4[r], sh, 64);
    }
    if (col == 0) {
#pragma unroll
        for (int r = 0; r < 4; ++r) sqP[quad * 4 + r][wv] = s4[r];
    }
    __syncthreads();
    if (t < 16) sq[p0 + t] = sqP[t][0] + sqP[t][1] + sqP[t][2] + sqP[t][3];
}

// ---------------------------------------------------------------------------
// kNN: Gram via MFMA + XCD swizzle; 4-chain selection with pure-DPP reduce.
// __launch_bounds__(256,4): LDS already caps at 4 blocks/CU, so let the
// allocator use 128 VGPRs — keeps kk/rr sorted lists in registers (R11's
// VGPR=64 build spilled them to scratch: ~4x instruction bloat).
// ---------------------------------------------------------------------------
__global__ __launch_bounds__(256, 4) void k_knn(
    const short* __restrict__ hS, const float* __restrict__ sq, int* __restrict__ idxout)
{
    int xcd = blockIdx.x & 7;
    int s_  = blockIdx.x >> 3;
    int b   = xcd + ((s_ >> 5) << 3);
    int n0  = (s_ & 31) << 4;
    int t   = threadIdx.x;

    __shared__ unsigned int keysLDS[16 * 512];
    __shared__ float sqS[512];

    if (t < 128) ((float4*)sqS)[t] = ((const float4*)(sq + (size_t)b * Nn))[t];
    __syncthreads();

    int wv = t >> 6, lane = t & 63, col = lane & 15, quad = lane >> 4;
    const size_t rowbase = (size_t)b * Nn * Hh;

    bf16x8 AH[2], AM[2], AL[2];
    {
        const short* crow = hS + rowbase + (size_t)(n0 + col) * Hh;
#pragma unroll
        for (int ks = 0; ks < 2; ++ks) {
            int aoff = ks * 32 + quad * 8;
            AH[ks] = *(const bf16x8*)(crow + 0 * PLN + aoff);
            AM[ks] = *(const bf16x8*)(crow + 1 * PLN + aoff);
            AL[ks] = *(const bf16x8*)(crow + 2 * PLN + aoff);
        }
    }
    float sqcr[4];
#pragma unroll
    for (int r_ = 0; r_ < 4; ++r_) sqcr[r_] = sqS[n0 + quad * 4 + r_];

    for (int i = 0; i < 8; ++i) {
        int nt = wv * 8 + i;
        const short* prow = hS + rowbase + (size_t)(nt * 16 + col) * Hh;
        f32x4 acc = (f32x4){0.f, 0.f, 0.f, 0.f};
#pragma unroll
        for (int ks = 0; ks < 2; ++ks) {
            int aoff = ks * 32 + quad * 8;
            bf16x8 BH = *(const bf16x8*)(prow + 0 * PLN + aoff);
            bf16x8 BM = *(const bf16x8*)(prow + 1 * PLN + aoff);
            bf16x8 BL = *(const bf16x8*)(prow + 2 * PLN + aoff);
            MFMA6(acc, AH[ks], AM[ks], AL[ks], BH, BM, BL)
        }
        float sqp = sqS[nt * 16 + col];
#pragma unroll
        for (int r_ = 0; r_ < 4; ++r_) {
            int ctr = quad * 4 + r_;
            float d = sqcr[r_] + sqp - 2.0f * acc[r_];
            unsigned int u = __float_as_uint(d);
            u = ((int)u < 0) ? ~u : (u | 0x80000000u);
            keysLDS[ctr * 512 + nt * 16 + col] = u;
        }
    }
    __syncthreads();

    unsigned int kk[4][8];
    int rr[4][8];
#pragma unroll
    for (int s = 0; s < 4; ++s) {
        int jj = wv * 4 + s;
        const uint4* kp = (const uint4*)&keysLDS[jj * 512 + (lane << 3)];
        uint4 A = kp[0], Bq = kp[1];
        kk[s][0] = A.x;  kk[s][1] = A.y;  kk[s][2] = A.z;  kk[s][3] = A.w;
        kk[s][4] = Bq.x; kk[s][5] = Bq.y; kk[s][6] = Bq.z; kk[s][7] = Bq.w;
#pragma unroll
        for (int q = 0; q < 8; ++q) rr[s][q] = q;
    }

#define CE(s, i, j_) { \
    bool sw = (kk[s][i] > kk[s][j_]) || (kk[s][i] == kk[s][j_] && rr[s][i] > rr[s][j_]); \
    unsigned int tk = sw ? kk[s][i] : kk[s][j_]; kk[s][i] = sw ? kk[s][j_] : kk[s][i]; kk[s][j_] = tk; \
    int tr = sw ? rr[s][i] : rr[s][j_]; rr[s][i] = sw ? rr[s][j_] : rr[s][i]; rr[s][j_] = tr; }
#pragma unroll
    for (int s = 0; s < 4; ++s) {
        CE(s,0,1) CE(s,2,3) CE(s,4,5) CE(s,6,7)
        CE(s,0,2) CE(s,1,3) CE(s,4,6) CE(s,5,7)
        CE(s,1,2) CE(s,5,6)
        CE(s,0,4) CE(s,1,5) CE(s,2,6) CE(s,3,7)
        CE(s,2,4) CE(s,3,5)
        CE(s,1,2) CE(s,3,4) CE(s,5,6)
    }
#undef CE

    int outbase[4];
#pragma unroll
    for (int s = 0; s < 4; ++s) outbase[s] = (b * Nn + n0 + wv * 4 + s) * Kk;

    for (int iter = 0; iter < Kk; ++iter) {
        unsigned int mv[4];
#pragma unroll
        for (int s = 0; s < 4; ++s) mv[s] = kk[s][0];
        // pure-DPP 64-lane min all-reduce; full min lands in lane 63
#define DSTEP(ctrl) { \
        _Pragma("unroll") \
        for (int s = 0; s < 4; ++s) { \
            unsigned int ov = (unsigned int)__builtin_amdgcn_update_dpp((int)mv[s], (int)mv[s], ctrl, 0xF, 0xF, false); \
            mv[s] = (ov < mv[s]) ? ov : mv[s]; } }
        DSTEP(0xB1)    // quad_perm xor1
        DSTEP(0x4E)    // quad_perm xor2
        DSTEP(0x124)   // row_ror:4
        DSTEP(0x128)   // row_ror:8     -> each row16 uniform
        DSTEP(0x142)   // row_bcast15
        DSTEP(0x143)   // row_bcast31   -> lane63 holds full min
#undef DSTEP
        unsigned int m[4];
#pragma unroll
        for (int s = 0; s < 4; ++s)
            m[s] = (unsigned int)__builtin_amdgcn_readlane((int)mv[s], 63);
#pragma unroll
        for (int s = 0; s < 4; ++s) {
            unsigned long long bal = __ballot(kk[s][0] == m[s]);
            int wn = __ffsll(bal) - 1;
            if (lane == wn) {
                idxout[outbase[s] + iter] = (lane << 3) + rr[s][0];
#pragma unroll
                for (int q = 0; q < 7; ++q) { kk[s][q] = kk[s][q + 1]; rr[s][q] = rr[s][q + 1]; }
                kk[s][7] = 0xFFFFFFFFu;
            }
        }
    }
}

// ---------------------------------------------------------------------------
// EdgeConv via MFMA, base/delta, XCD swizzle (unchanged)
// ---------------------------------------------------------------------------
__global__ __launch_bounds__(256, 4) void k_edge(
    const short* __restrict__ hS,
    const int* __restrict__ idx,
    const short* __restrict__ wS,
    const float* __restrict__ g, const float* __restrict__ bb_,
    short* __restrict__ hSout, float* __restrict__ sqout)
{
    __shared__ short wLDS[3][64 * 72];
    __shared__ float baseS[16 * 68];
    __shared__ int   idxS[256];

    int t   = threadIdx.x;
    int xcd = blockIdx.x & 7;
    int s_  = blockIdx.x >> 3;
    int b   = xcd + ((s_ >> 5) << 3);
    int p0  = b * Nn + ((s_ & 31) << 4);

    idxS[t] = idx[p0 * Kk + t];
#pragma unroll
    for (int it = 0; it < 6; ++it) {
        int f = it * 256 + t;
        int plane = f >> 9;
        int i8 = f & 511;
        int o = i8 >> 3, c8 = i8 & 7;
        uint4 v = ((const uint4*)(wS + (size_t)(3 + plane) * 4096))[i8];
        *(uint4*)&wLDS[plane][o * 72 + c8 * 8] = v;
    }
    __syncthreads();

    int wv = t >> 6, lane = t & 63, col = lane & 15, quad = lane >> 4;

    {
        f32x4 bacc = (f32x4){0.f, 0.f, 0.f, 0.f};
        const short* hrow = hS + (size_t)(p0 + col) * Hh;
#pragma unroll
        for (int ks = 0; ks < 2; ++ks) {
            int aoff = ks * 32 + quad * 8;
            bf16x8 AH = *(const bf16x8*)(hrow + 0 * PLN + aoff);
            bf16x8 AM = *(const bf16x8*)(hrow + 1 * PLN + aoff);
            bf16x8 AL = *(const bf16x8*)(hrow + 2 * PLN + aoff);
            int boff = (wv * 16 + col) * 72 + aoff;
            bf16x8 BH = *(bf16x8*)&wLDS[0][boff];
            bf16x8 BM = *(bf16x8*)&wLDS[1][boff];
            bf16x8 BL = *(bf16x8*)&wLDS[2][boff];
            MFMA6(bacc, AH, AM, AL, BH, BM, BL)
        }
#pragma unroll
        for (int r_ = 0; r_ < 4; ++r_)
            baseS[(quad * 4 + r_) * 68 + wv * 16 + col] = bacc[r_];
    }
    __syncthreads();

#pragma unroll
    for (int it = 0; it < 6; ++it) {
        int f = it * 256 + t;
        int plane = f >> 9;
        int i8 = f & 511;
        int o = i8 >> 3, c8 = i8 & 7;
        uint4 v = ((const uint4*)(wS + (size_t)plane * 4096))[i8];
        *(uint4*)&wLDS[plane][o * 72 + c8 * 8] = v;
    }
    __syncthreads();

    const float inv = rsqrtf(1.0f + EPSf);
    float scv[4], bov[4];
#pragma unroll
    for (int nt = 0; nt < 4; ++nt) {
        scv[nt] = g[nt * 16 + col] * inv;
        bov[nt] = bb_[nt * 16 + col];
    }

    for (int pr = 0; pr < 2; ++pr) {
        bf16x8 A[2][2][3];
#pragma unroll
        for (int pt2 = 0; pt2 < 2; ++pt2) {
            int pl = wv * 4 + pr * 2 + pt2;
            int j = idxS[pl * 16 + col];
            const short* nrow = hS + ((size_t)(b * Nn) + j) * Hh;
#pragma unroll
            for (int ks = 0; ks < 2; ++ks) {
                int aoff = ks * 32 + quad * 8;
                A[pt2][ks][0] = *(const bf16x8*)(nrow + 0 * PLN + aoff);
                A[pt2][ks][1] = *(const bf16x8*)(nrow + 1 * PLN + aoff);
                A[pt2][ks][2] = *(const bf16x8*)(nrow + 2 * PLN + aoff);
            }
        }

        f32x4 acc[2][4];
#pragma unroll
        for (int pt2 = 0; pt2 < 2; ++pt2)
#pragma unroll
            for (int nt = 0; nt < 4; ++nt)
                acc[pt2][nt] = (f32x4){0.f, 0.f, 0.f, 0.f};

#pragma unroll
        for (int ks = 0; ks < 2; ++ks)
#pragma unroll
            for (int nt = 0; nt < 4; ++nt) {
                int boff = (nt * 16 + col) * 72 + ks * 32 + quad * 8;
                bf16x8 BH = *(bf16x8*)&wLDS[0][boff];
                bf16x8 BM = *(bf16x8*)&wLDS[1][boff];
                bf16x8 BL = *(bf16x8*)&wLDS[2][boff];
#pragma unroll
                for (int pt2 = 0; pt2 < 2; ++pt2) {
                    f32x4 a = acc[pt2][nt];
                    MFMA6(a, A[pt2][ks][0], A[pt2][ks][1], A[pt2][ks][2], BH, BM, BL)
                    acc[pt2][nt] = a;
                }
            }

#pragma unroll
        for (int pt2 = 0; pt2 < 2; ++pt2) {
            int pl = wv * 4 + pr * 2 + pt2;
            int pglob = p0 + pl;
            float res[4];
#pragma unroll
            for (int nt = 0; nt < 4; ++nt) {
                float base = baseS[pl * 68 + nt * 16 + col];
                f32x4 a = acc[pt2][nt];
                float v0 = fmaf(base + a[0], scv[nt], bov[nt]);
                float v1 = fmaf(base + a[1], scv[nt], bov[nt]);
                float v2 = fmaf(base + a[2], scv[nt], bov[nt]);
                float v3 = fmaf(base + a[3], scv[nt], bov[nt]);
                float vm = fmaxf(fmaxf(v0, v1), fmaxf(v2, v3));
                vm = fmaxf(vm, __shfl_xor(vm, 16));
                vm = fmaxf(vm, __shfl_xor(vm, 32));
                res[nt] = fmaxf(vm, 0.0f);
            }
            float rv = res[quad];
            short hs_, ms_, ls_;
            split3(rv, hs_, ms_, ls_);
            hSout[0 * PLN + (size_t)pglob * Hh + lane] = hs_;
            hSout[1 * PLN + (size_t)pglob * Hh + lane] = ms_;
            hSout[2 * PLN + (size_t)pglob * Hh + lane] = ls_;

            float s = res[0] * res[0] + res[1] * res[1]
                    + res[2] * res[2] + res[3] * res[3];
            s += __shfl_xor(s, 1);
            s += __shfl_xor(s, 2);
            s += __shfl_xor(s, 4);
            s += __shfl_xor(s, 8);
            if (lane == 0) sqout[pglob] = s;
        }
    }
}

// ---------------------------------------------------------------------------
// head via MFMA (unchanged)
// ---------------------------------------------------------------------------
__global__ __launch_bounds__(256) void k_head(
    const short* __restrict__ hS, const short* __restrict__ wSs1,
    const float* __restrict__ g1, const float* __restrict__ b1,
    const float* __restrict__ w2, const float* __restrict__ b2,
    float* __restrict__ out)
{
    __shared__ short wLDS[3][64 * 80];
    __shared__ float partS[16][4];

    int t  = threadIdx.x;
    int p0 = blockIdx.x * 16;

#pragma unroll
    for (int it = 0; it < 6; ++it) {
        int f = it * 256 + t;
        int plane = f >> 9, i8 = f & 511;
        int o = i8 >> 3, c8 = i8 & 7;
        uint4 v = ((const uint4*)(wSs1 + (size_t)plane * 4096))[i8];
        *(uint4*)&wLDS[plane][o * 80 + c8 * 8] = v;
    }
    __syncthreads();

    int wv = t >> 6, lane = t & 63, col = lane & 15, quad = lane >> 4;

    const short* crow = hS + (size_t)(p0 + col) * Hh;
    f32x4 acc = (f32x4){0.f, 0.f, 0.f, 0.f};
#pragma unroll
    for (int ks = 0; ks < 2; ++ks) {
        int aoff = ks * 32 + quad * 8;
        bf16x8 AH = *(const bf16x8*)(crow + 0 * PLN + aoff);
        bf16x8 AM = *(const bf16x8*)(crow + 1 * PLN + aoff);
        bf16x8 AL = *(const bf16x8*)(crow + 2 * PLN + aoff);
        int boff = (wv * 16 + col) * 80 + aoff;
        bf16x8 BH = *(bf16x8*)&wLDS[0][boff];
        bf16x8 BM = *(bf16x8*)&wLDS[1][boff];
        bf16x8 BL = *(bf16x8*)&wLDS[2][boff];
        MFMA6(acc, AH, AM, AL, BH, BM, BL)
    }

    int o = wv * 16 + col;
    const float inv = rsqrtf(1.0f + EPSf);
    float sc = g1[o] * inv, bo = b1[o], w2o = w2[o];
    float s4[4];
#pragma unroll
    for (int r = 0; r < 4; ++r) {
        float a = fmaxf(fmaf(acc[r], sc, bo), 0.0f);
        s4[r] = a * w2o;
    }
#pragma unroll
    for (int sh = 1; sh < 16; sh <<= 1) {
#pragma unroll
        for (int r = 0; r < 4; ++r) s4[r] += __shfl_xor(s4[r], sh, 64);
    }
    if (col == 0) {
#pragma unroll
        for (int r = 0; r < 4; ++r) partS[quad * 4 + r][wv] = s4[r];
    }
    __syncthreads();
    if (t < 16)
        out[p0 + t] = partS[t][0] + partS[t][1] + partS[t][2] + partS[t][3] + b2[0];
}

// ---------------------------------------------------------------------------
extern "C" void kernel_launch(void* const* d_in, const int* in_sizes, int n_in,
                              void* d_out, int out_size, void* d_ws, size_t ws_size,
                              hipStream_t stream)
{
    const float* x    = (const float*)d_in[0];
    const float* w_t1 = (const float*)d_in[1];
    const float* g_t1 = (const float*)d_in[2];
    const float* b_t1 = (const float*)d_in[3];
    const float* w_t2 = (const float*)d_in[4];
    const float* g_t2 = (const float*)d_in[5];
    const float* b_t2 = (const float*)d_in[6];
    const float* w_nb = (const float*)d_in[7];
    const float* g_nb = (const float*)d_in[8];
    const float* b_nb = (const float*)d_in[9];
    const float* w_s1 = (const float*)d_in[10];
    const float* g_s1 = (const float*)d_in[11];
    const float* b_s1 = (const float*)d_in[12];
    const float* w_s2 = (const float*)d_in[13];
    const float* b_s2 = (const float*)d_in[14];
    float* out = (float*)d_out;

    float* sq  = (float*)d_ws;
    int*   idx = (int*)(sq + (size_t)Bn * Nn);
    short* hSa = (short*)(idx + (size_t)Bn * Nn * Kk);
    short* hSb = hSa + 3 * PLN;
    short* wS  = hSb + 3 * PLN;            // 18 planes x 4096 shorts

    k_prep<<<64, 256, 0, stream>>>(w_nb, w_t2, w_s1, wS);
    k_t12<<<Bn * Nn / 16, 256, 0, stream>>>(x, w_t1, g_t1, b_t1,
                                            wS + (size_t)12 * 4096, g_t2, b_t2,
                                            hSa, sq);

    const short* hSin = hSa;
    short* hSout = hSb;
    for (int r = 0; r < Rr; ++r) {
        k_knn<<<Bn * (Nn / 16), 256, 0, stream>>>(hSin, sq, idx);
        k_edge<<<Bn * Nn / 16, 256, 0, stream>>>(hSin, idx,
            wS + (size_t)r * 6 * 4096, g_nb + r * Hh, b_nb + r * Hh,
            hSout, sq);
        const short* ts = hSout; hSout = (short*)hSin; hSin = ts;
    }
    k_head<<<Bn * Nn / 16, 256, 0, stream>>>(hSin, wS + (size_t)15 * 4096,
                                             g_s1, b_s1, w_s2, b_s2, out);
}